// Round 1
// baseline (3372.408 us; speedup 1.0000x reference)
//
#include <hip/hip_runtime.h>
#include <cstddef>
#include <cstdint>

// Problem constants (fixed by reference)
#define DMODEL 768
#define DINNER 1536
#define NSTATE 16
#define LSEQ   2048
#define NB     2
#define NTOK   (NB*LSEQ)        // 4096 tokens
#define NBCDT  33               // 1 + 2*16

__device__ __forceinline__ float silu_f(float x) { return x / (1.f + expf(-x)); }

// ---------------------------------------------------------------------------
// Kernel 1: LayerNorm.  one block per token row (4096 blocks x 256 threads)
// ---------------------------------------------------------------------------
__global__ void ln_kernel(const float* __restrict__ x,
                          const float* __restrict__ g,
                          const float* __restrict__ be,
                          float* __restrict__ xn) {
    int row = blockIdx.x;
    int tid = threadIdx.x;
    const float* xr = x + (size_t)row * DMODEL;
    float s = 0.f, ss = 0.f;
    for (int i = tid; i < DMODEL; i += 256) {
        float v = xr[i];
        s += v; ss += v * v;
    }
    // wave reduce (64 lanes)
    for (int o = 32; o >= 1; o >>= 1) {
        s  += __shfl_xor(s,  o, 64);
        ss += __shfl_xor(ss, o, 64);
    }
    __shared__ float sS[4], sSS[4];
    int w = tid >> 6;
    if ((tid & 63) == 0) { sS[w] = s; sSS[w] = ss; }
    __syncthreads();
    s  = sS[0] + sS[1] + sS[2] + sS[3];
    ss = sSS[0] + sSS[1] + sSS[2] + sSS[3];
    float mu = s / DMODEL;
    float var = ss / DMODEL - mu * mu;
    float rstd = rsqrtf(var + 1e-5f);
    float* xo = xn + (size_t)row * DMODEL;
    for (int i = tid; i < DMODEL; i += 256)
        xo[i] = (xr[i] - mu) * rstd * g[i] + be[i];
}

// ---------------------------------------------------------------------------
// Kernel 2: xz GEMM.  M=4096 (tokens), K=768, N=6144 (= [f_inw | b_inw]).
// Epilogue: cols [0,1536) -> xi[dir], cols [1536,3072) -> silu -> sz[dir].
// xi/sz are stored indexed by ORIGINAL l for both directions.
// 64x64 tile, 256 threads, 4x4 per thread, TK=16.
// ---------------------------------------------------------------------------
#define TK 16
__global__ __launch_bounds__(256)
void gemm_xz(const float* __restrict__ xn,
             const float* __restrict__ fw,   // [768,3072]
             const float* __restrict__ bw,   // [768,3072]
             float* __restrict__ xi,         // [2][4096][1536]
             float* __restrict__ sz) {       // [2][4096][1536]
    __shared__ float As[TK][64 + 1];
    __shared__ float Bs[TK][64 + 1];
    int bm = blockIdx.y * 64;
    int bn = blockIdx.x * 64;
    int tid = threadIdx.x;
    int tx = tid & 15, ty = tid >> 4;
    float acc[4][4] = {};
    for (int k0 = 0; k0 < DMODEL; k0 += TK) {
        #pragma unroll
        for (int i = 0; i < 4; i++) {
            int idx = tid + i * 256;
            int m = idx >> 4, k = idx & 15;
            As[k][m] = xn[(size_t)(bm + m) * DMODEL + k0 + k];
        }
        #pragma unroll
        for (int i = 0; i < 4; i++) {
            int idx = tid + i * 256;
            int k = idx >> 6, n = idx & 63;
            int gn = bn + n;
            const float* w = (gn < 3072) ? fw : bw;
            int col = gn & 3071;   // gn % 3072 (3072 = 0xC00, tiles never cross)
            if (gn >= 3072) col = gn - 3072;
            Bs[k][n] = w[(size_t)(k0 + k) * 3072 + col];
        }
        __syncthreads();
        #pragma unroll
        for (int k = 0; k < TK; k++) {
            float a[4], b[4];
            #pragma unroll
            for (int i = 0; i < 4; i++) a[i] = As[k][ty * 4 + i];
            #pragma unroll
            for (int j = 0; j < 4; j++) b[j] = Bs[k][tx * 4 + j];
            #pragma unroll
            for (int i = 0; i < 4; i++)
                #pragma unroll
                for (int j = 0; j < 4; j++)
                    acc[i][j] = fmaf(a[i], b[j], acc[i][j]);
        }
        __syncthreads();
    }
    #pragma unroll
    for (int i = 0; i < 4; i++) {
        int row = bm + ty * 4 + i;
        #pragma unroll
        for (int j = 0; j < 4; j++) {
            int gn = bn + tx * 4 + j;
            int dir = gn / 3072;
            int col = gn - dir * 3072;
            float v = acc[i][j];
            size_t base = ((size_t)dir * NTOK + row) * DINNER;
            if (col < DINNER) xi[base + col] = v;
            else              sz[base + col - DINNER] = silu_f(v);
        }
    }
}

// ---------------------------------------------------------------------------
// Kernel 3: depthwise causal conv (k=4) + bias + SiLU.
// Output xc indexed by SCAN TIME t; input xi indexed by original l.
// For dir=1 the logical sequence is flipped: orig(u) = L-1-u.
// ---------------------------------------------------------------------------
__global__ void conv_silu(const float* __restrict__ xi,
                          const float* __restrict__ f_cw, const float* __restrict__ f_cb,
                          const float* __restrict__ b_cw, const float* __restrict__ b_cb,
                          float* __restrict__ xc) {
    size_t gid = (size_t)blockIdx.x * 256 + threadIdx.x;
    const size_t total = (size_t)2 * NTOK * DINNER;
    if (gid >= total) return;
    int d = (int)(gid % DINNER);
    size_t r = gid / DINNER;          // (dir*2+b)*LSEQ + t
    int t = (int)(r % LSEQ);
    int b = (int)((r / LSEQ) % NB);
    int dir = (int)(r / (LSEQ * NB));
    const float* cw = dir ? b_cw : f_cw;
    const float* cb = dir ? b_cb : f_cb;
    float acc = cb[d];
    size_t xib = ((size_t)dir * NTOK + (size_t)b * LSEQ) * DINNER;
    #pragma unroll
    for (int k = 0; k < 4; k++) {
        int u = t - 3 + k;
        if (u < 0) continue;
        int l = dir ? (LSEQ - 1 - u) : u;
        acc = fmaf(cw[d * 4 + k], xi[xib + (size_t)l * DINNER + d], acc);
    }
    xc[gid] = silu_f(acc);
}

// ---------------------------------------------------------------------------
// Kernel 4: bcdt = xc @ xw  ([1536] -> [33] per token, per dir)
// one thread per (row, j) output.
// ---------------------------------------------------------------------------
__global__ void bcdt_kernel(const float* __restrict__ xc,
                            const float* __restrict__ f_xw,
                            const float* __restrict__ b_xw,
                            float* __restrict__ bcdt) {
    int gid = blockIdx.x * 256 + threadIdx.x;
    const int total = 2 * NTOK * NBCDT;
    if (gid >= total) return;
    int j = gid % NBCDT;
    int r = gid / NBCDT;              // (dir*2+b)*LSEQ + t
    int dir = r / NTOK;
    const float* xw = dir ? b_xw : f_xw;
    const float* xr = xc + (size_t)r * DINNER;
    float acc = 0.f;
    for (int k = 0; k < DINNER; k++)
        acc = fmaf(xr[k], xw[(size_t)k * NBCDT + j], acc);
    bcdt[(size_t)r * NBCDT + j] = acc;
}

// ---------------------------------------------------------------------------
// Kernel 5: selective scan.  16 lanes per channel (lane = state s).
// block = 256 threads = 16 channels; grid = (96 channel-groups, 2 b, 2 dir).
// ---------------------------------------------------------------------------
__global__ __launch_bounds__(256)
void scan_kernel(const float* __restrict__ xc,
                 const float* __restrict__ bcdt,
                 const float* __restrict__ sz,
                 const float* __restrict__ f_dtw, const float* __restrict__ f_dtb,
                 const float* __restrict__ f_Alog, const float* __restrict__ f_D,
                 const float* __restrict__ b_dtw, const float* __restrict__ b_dtb,
                 const float* __restrict__ b_Alog, const float* __restrict__ b_D,
                 float* __restrict__ yv) {
    int tid = threadIdx.x;
    int s = tid & 15;
    int c = tid >> 4;
    int d = blockIdx.x * 16 + c;
    int b = blockIdx.y, dir = blockIdx.z;
    const float* dtw  = dir ? b_dtw  : f_dtw;
    const float* dtb  = dir ? b_dtb  : f_dtb;
    const float* Alog = dir ? b_Alog : f_Alog;
    const float* Dp   = dir ? b_D    : f_D;
    float al = Alog[d * NSTATE + s];
    al = fminf(fmaxf(al, -6.f), 6.f);
    float A_s = -expf(al);
    float dtw_d = dtw[d], dtb_d = dtb[d], D_d = Dp[d];
    float h = 0.f;
    size_t rbase = (size_t)dir * NTOK + (size_t)b * LSEQ;   // row base
    const float* bc0 = bcdt + rbase * NBCDT;
    const float* xc0 = xc + rbase * DINNER;
    const float* sz0 = sz + rbase * DINNER;
    float* yv0 = yv + rbase * DINNER;
    for (int t = 0; t < LSEQ; t++) {
        const float* bc = bc0 + (size_t)t * NBCDT;
        float dt_raw = bc[0];
        float Bv = bc[1 + s];
        float Cv = bc[1 + NSTATE + s];
        float xv = xc0[(size_t)t * DINNER + d];
        float u = fmaf(dt_raw, dtw_d, dtb_d);
        // stable softplus
        float dt = fmaxf(u, 0.f) + log1pf(expf(-fabsf(u)));
        float dA = expf(dt * A_s);
        h = fmaf(dA, h, dt * Bv * xv);
        h = fminf(fmaxf(h, -1e4f), 1e4f);
        float p = h * Cv;
        p += __shfl_xor(p, 1, 16);
        p += __shfl_xor(p, 2, 16);
        p += __shfl_xor(p, 4, 16);
        p += __shfl_xor(p, 8, 16);
        if (s == 0) {
            int l = dir ? (LSEQ - 1 - t) : t;
            float szv = sz0[(size_t)l * DINNER + d];
            yv0[(size_t)t * DINNER + d] = (p + xv * D_d) * szv;
        }
    }
}

// ---------------------------------------------------------------------------
// Kernel 6: output GEMM + blend + residual.
// out[row, n] = a * (yv_f[row] @ f_outw)[n] + (1-a) * (yv_b[flip(row)] @ b_outw)[n] + x[row,n]
// Fused as one K=3072 GEMM; B tile scaled by a / (1-a) at load.
// ---------------------------------------------------------------------------
__global__ __launch_bounds__(256)
void gemm_out(const float* __restrict__ yv,
              const float* __restrict__ f_outw,   // [1536,768]
              const float* __restrict__ b_outw,
              const float* __restrict__ x,
              const float* __restrict__ alpha,
              float* __restrict__ out) {
    __shared__ float As[TK][64 + 1];
    __shared__ float Bs[TK][64 + 1];
    float a_blend = 1.f / (1.f + expf(-alpha[0]));
    int bm = blockIdx.y * 64;
    int bn = blockIdx.x * 64;
    int tid = threadIdx.x;
    int tx = tid & 15, ty = tid >> 4;
    float acc[4][4] = {};
    for (int k0 = 0; k0 < 2 * DINNER; k0 += TK) {
        #pragma unroll
        for (int i = 0; i < 4; i++) {
            int idx = tid + i * 256;
            int m = idx >> 4, k = idx & 15;
            int row = bm + m;
            int bb = row >> 11;           // /2048
            int l = row & 2047;
            int gk = k0 + k;
            float v;
            if (gk < DINNER) {
                v = yv[((size_t)0 * NTOK + row) * DINNER + gk];
            } else {
                size_t r2 = (size_t)NTOK + (size_t)bb * LSEQ + (LSEQ - 1 - l);
                v = yv[r2 * DINNER + (gk - DINNER)];
            }
            As[k][m] = v;
        }
        #pragma unroll
        for (int i = 0; i < 4; i++) {
            int idx = tid + i * 256;
            int k = idx >> 6, n = idx & 63;
            int gk = k0 + k;
            int gn = bn + n;
            float v;
            if (gk < DINNER) v = a_blend * f_outw[(size_t)gk * DMODEL + gn];
            else             v = (1.f - a_blend) * b_outw[(size_t)(gk - DINNER) * DMODEL + gn];
            Bs[k][n] = v;
        }
        __syncthreads();
        #pragma unroll
        for (int k = 0; k < TK; k++) {
            float a[4], b[4];
            #pragma unroll
            for (int i = 0; i < 4; i++) a[i] = As[k][ty * 4 + i];
            #pragma unroll
            for (int j = 0; j < 4; j++) b[j] = Bs[k][tx * 4 + j];
            #pragma unroll
            for (int i = 0; i < 4; i++)
                #pragma unroll
                for (int j = 0; j < 4; j++)
                    acc[i][j] = fmaf(a[i], b[j], acc[i][j]);
        }
        __syncthreads();
    }
    #pragma unroll
    for (int i = 0; i < 4; i++) {
        int row = bm + ty * 4 + i;
        #pragma unroll
        for (int j = 0; j < 4; j++) {
            int gn = bn + tx * 4 + j;
            out[(size_t)row * DMODEL + gn] = acc[i][j] + x[(size_t)row * DMODEL + gn];
        }
    }
}

// ---------------------------------------------------------------------------
extern "C" void kernel_launch(void* const* d_in, const int* in_sizes, int n_in,
                              void* d_out, int out_size, void* d_ws, size_t ws_size,
                              hipStream_t stream) {
    const float* x     = (const float*)d_in[0];
    const float* ln_g  = (const float*)d_in[1];
    const float* ln_b  = (const float*)d_in[2];
    const float* alpha = (const float*)d_in[3];
    const float* f_inw  = (const float*)d_in[4];
    const float* f_cw   = (const float*)d_in[5];
    const float* f_cb   = (const float*)d_in[6];
    const float* f_xw   = (const float*)d_in[7];
    const float* f_dtw  = (const float*)d_in[8];
    const float* f_dtb  = (const float*)d_in[9];
    const float* f_Alog = (const float*)d_in[10];
    const float* f_D    = (const float*)d_in[11];
    const float* f_outw = (const float*)d_in[12];
    const float* b_inw  = (const float*)d_in[13];
    const float* b_cw   = (const float*)d_in[14];
    const float* b_cb   = (const float*)d_in[15];
    const float* b_xw   = (const float*)d_in[16];
    const float* b_dtw  = (const float*)d_in[17];
    const float* b_dtb  = (const float*)d_in[18];
    const float* b_Alog = (const float*)d_in[19];
    const float* b_D    = (const float*)d_in[20];
    const float* b_outw = (const float*)d_in[21];
    float* out = (float*)d_out;

    // Workspace layout (floats):
    float* ws = (float*)d_ws;
    const size_t xn_sz = (size_t)NTOK * DMODEL;        //  3,145,728
    const size_t big   = (size_t)2 * NTOK * DINNER;    // 12,582,912
    float* xn   = ws;
    float* xi   = xn + xn_sz;        // [2][4096][1536] (orig l); later reused as yv
    float* sz   = xi + big;          // [2][4096][1536] (orig l), silu(z)
    float* xc   = sz + big;          // [2][4096][1536] (scan t)
    float* bcdt = xc + big;          // [2][4096][33]   (scan t)
    float* yv   = xi;                // alias: xi dead after conv

    // 1. LayerNorm
    ln_kernel<<<NTOK, 256, 0, stream>>>(x, ln_g, ln_b, xn);
    // 2. xz GEMM (both dirs)
    {
        dim3 grid(6144 / 64, 4096 / 64);
        gemm_xz<<<grid, 256, 0, stream>>>(xn, f_inw, b_inw, xi, sz);
    }
    // 3. conv + silu
    {
        size_t total = (size_t)2 * NTOK * DINNER;
        conv_silu<<<(total + 255) / 256, 256, 0, stream>>>(xi, f_cw, f_cb, b_cw, b_cb, xc);
    }
    // 4. bcdt
    {
        int total = 2 * NTOK * NBCDT;
        bcdt_kernel<<<(total + 255) / 256, 256, 0, stream>>>(xc, f_xw, b_xw, bcdt);
    }
    // 5. scan
    {
        dim3 grid(DINNER / 16, NB, 2);
        scan_kernel<<<grid, 256, 0, stream>>>(xc, bcdt, sz,
                                              f_dtw, f_dtb, f_Alog, f_D,
                                              b_dtw, b_dtb, b_Alog, b_D, yv);
    }
    // 6. out GEMM + blend + residual
    {
        dim3 grid(DMODEL / 64, NTOK / 64);
        gemm_out<<<grid, 256, 0, stream>>>(yv, f_outw, b_outw, x, alpha, out);
    }
}

// Round 2
// 3121.551 us; speedup vs baseline: 1.0804x; 1.0804x over previous
//
#include <hip/hip_runtime.h>
#include <cstddef>
#include <cstdint>

// Problem constants (fixed by reference)
#define DMODEL 768
#define DINNER 1536
#define NSTATE 16
#define LSEQ   2048
#define NB     2
#define NTOK   (NB*LSEQ)        // 4096 tokens
#define NBCDT  33               // 1 + 2*16

// Chunked scan parameters
#define TC     128              // timesteps per chunk
#define NCHUNK (LSEQ/TC)        // 16
#define SUMSZ  (NCHUNK*4*DINNER*NSTATE)   // 16*4*24576 = 1,572,864 floats

__device__ __forceinline__ float silu_f(float x) { return x / (1.f + expf(-x)); }
__device__ __forceinline__ float clip1e4(float x) { return fminf(fmaxf(x, -1e4f), 1e4f); }

// ---------------------------------------------------------------------------
// Kernel 1: LayerNorm.  one block per token row (4096 blocks x 256 threads)
// ---------------------------------------------------------------------------
__global__ void ln_kernel(const float* __restrict__ x,
                          const float* __restrict__ g,
                          const float* __restrict__ be,
                          float* __restrict__ xn) {
    int row = blockIdx.x;
    int tid = threadIdx.x;
    const float* xr = x + (size_t)row * DMODEL;
    float s = 0.f, ss = 0.f;
    for (int i = tid; i < DMODEL; i += 256) {
        float v = xr[i];
        s += v; ss += v * v;
    }
    for (int o = 32; o >= 1; o >>= 1) {
        s  += __shfl_xor(s,  o, 64);
        ss += __shfl_xor(ss, o, 64);
    }
    __shared__ float sS[4], sSS[4];
    int w = tid >> 6;
    if ((tid & 63) == 0) { sS[w] = s; sSS[w] = ss; }
    __syncthreads();
    s  = sS[0] + sS[1] + sS[2] + sS[3];
    ss = sSS[0] + sSS[1] + sSS[2] + sSS[3];
    float mu = s / DMODEL;
    float var = ss / DMODEL - mu * mu;
    float rstd = rsqrtf(var + 1e-5f);
    float* xo = xn + (size_t)row * DMODEL;
    for (int i = tid; i < DMODEL; i += 256)
        xo[i] = (xr[i] - mu) * rstd * g[i] + be[i];
}

// ---------------------------------------------------------------------------
// Kernel 2: xz GEMM.  M=4096 (tokens), K=768, N=6144 (= [f_inw | b_inw]).
// ---------------------------------------------------------------------------
#define TK 16
__global__ __launch_bounds__(256)
void gemm_xz(const float* __restrict__ xn,
             const float* __restrict__ fw,   // [768,3072]
             const float* __restrict__ bw,   // [768,3072]
             float* __restrict__ xi,         // [2][4096][1536]
             float* __restrict__ sz) {       // [2][4096][1536]
    __shared__ float As[TK][64 + 1];
    __shared__ float Bs[TK][64 + 1];
    int bm = blockIdx.y * 64;
    int bn = blockIdx.x * 64;
    int tid = threadIdx.x;
    int tx = tid & 15, ty = tid >> 4;
    float acc[4][4] = {};
    for (int k0 = 0; k0 < DMODEL; k0 += TK) {
        #pragma unroll
        for (int i = 0; i < 4; i++) {
            int idx = tid + i * 256;
            int m = idx >> 4, k = idx & 15;
            As[k][m] = xn[(size_t)(bm + m) * DMODEL + k0 + k];
        }
        #pragma unroll
        for (int i = 0; i < 4; i++) {
            int idx = tid + i * 256;
            int k = idx >> 6, n = idx & 63;
            int gn = bn + n;
            const float* w = (gn < 3072) ? fw : bw;
            int col = (gn < 3072) ? gn : (gn - 3072);
            Bs[k][n] = w[(size_t)(k0 + k) * 3072 + col];
        }
        __syncthreads();
        #pragma unroll
        for (int k = 0; k < TK; k++) {
            float a[4], b[4];
            #pragma unroll
            for (int i = 0; i < 4; i++) a[i] = As[k][ty * 4 + i];
            #pragma unroll
            for (int j = 0; j < 4; j++) b[j] = Bs[k][tx * 4 + j];
            #pragma unroll
            for (int i = 0; i < 4; i++)
                #pragma unroll
                for (int j = 0; j < 4; j++)
                    acc[i][j] = fmaf(a[i], b[j], acc[i][j]);
        }
        __syncthreads();
    }
    #pragma unroll
    for (int i = 0; i < 4; i++) {
        int row = bm + ty * 4 + i;
        #pragma unroll
        for (int j = 0; j < 4; j++) {
            int gn = bn + tx * 4 + j;
            int dir = gn / 3072;
            int col = gn - dir * 3072;
            float v = acc[i][j];
            size_t base = ((size_t)dir * NTOK + row) * DINNER;
            if (col < DINNER) xi[base + col] = v;
            else              sz[base + col - DINNER] = silu_f(v);
        }
    }
}

// ---------------------------------------------------------------------------
// Kernel 3: depthwise causal conv (k=4) + bias + SiLU.
// ---------------------------------------------------------------------------
__global__ void conv_silu(const float* __restrict__ xi,
                          const float* __restrict__ f_cw, const float* __restrict__ f_cb,
                          const float* __restrict__ b_cw, const float* __restrict__ b_cb,
                          float* __restrict__ xc) {
    size_t gid = (size_t)blockIdx.x * 256 + threadIdx.x;
    const size_t total = (size_t)2 * NTOK * DINNER;
    if (gid >= total) return;
    int d = (int)(gid % DINNER);
    size_t r = gid / DINNER;          // (dir*2+b)*LSEQ + t
    int t = (int)(r % LSEQ);
    int b = (int)((r / LSEQ) % NB);
    int dir = (int)(r / (LSEQ * NB));
    const float* cw = dir ? b_cw : f_cw;
    const float* cb = dir ? b_cb : f_cb;
    float acc = cb[d];
    size_t xib = ((size_t)dir * NTOK + (size_t)b * LSEQ) * DINNER;
    #pragma unroll
    for (int k = 0; k < 4; k++) {
        int u = t - 3 + k;
        if (u < 0) continue;
        int l = dir ? (LSEQ - 1 - u) : u;
        acc = fmaf(cw[d * 4 + k], xi[xib + (size_t)l * DINNER + d], acc);
    }
    xc[gid] = silu_f(acc);
}

// ---------------------------------------------------------------------------
// Kernel 4: bcdt = xc @ xw  -- tiled skinny GEMM. M=8192, N=33, K=1536.
// block = 256 threads handles 64 rows; thread (m = tid>>2, jq = tid&3)
// owns cols j = jq + 4*jj.
// ---------------------------------------------------------------------------
__global__ __launch_bounds__(256)
void bcdt_gemm(const float* __restrict__ xc,
               const float* __restrict__ f_xw,
               const float* __restrict__ b_xw,
               float* __restrict__ bcdt) {
    __shared__ float As[64][33];     // row pad -> stride 33 breaks conflicts
    __shared__ float Ws[32 * 33];
    int r0 = blockIdx.x * 64;
    const float* xw = (r0 >= NTOK) ? b_xw : f_xw;
    int tid = threadIdx.x;
    int m = tid >> 2, jq = tid & 3;
    float acc[9] = {};
    for (int k0 = 0; k0 < DINNER; k0 += 32) {
        for (int i = tid; i < 64 * 32; i += 256) {
            int mm = i >> 5, k = i & 31;
            As[mm][k] = xc[((size_t)r0 + mm) * DINNER + k0 + k];
        }
        for (int i = tid; i < 32 * 33; i += 256)
            Ws[i] = xw[(size_t)k0 * 33 + i];
        __syncthreads();
        #pragma unroll 8
        for (int k = 0; k < 32; k++) {
            float a = As[m][k];
            #pragma unroll
            for (int jj = 0; jj < 9; jj++) {
                int j = jq + jj * 4;
                if (j < 33) acc[jj] = fmaf(a, Ws[k * 33 + j], acc[jj]);
            }
        }
        __syncthreads();
    }
    #pragma unroll
    for (int jj = 0; jj < 9; jj++) {
        int j = jq + jj * 4;
        if (j < 33) bcdt[((size_t)r0 + m) * 33 + j] = acc[jj];
    }
}

// ---------------------------------------------------------------------------
// Kernel 5a: chunked scan phase 1 -- per-chunk local scan.
// grid (96 ch-groups, NCHUNK, 4=dir*2+b), block 256 = 16 ch x 16 states.
// Outputs per (chunk,dirb,d,s): P = prod dA, hloc = local h at chunk end.
// ---------------------------------------------------------------------------
__global__ __launch_bounds__(256)
void scan_p1(const float* __restrict__ xc, const float* __restrict__ bcdt,
             const float* __restrict__ f_dtw, const float* __restrict__ f_dtb,
             const float* __restrict__ f_Alog,
             const float* __restrict__ b_dtw, const float* __restrict__ b_dtb,
             const float* __restrict__ b_Alog,
             float* __restrict__ Pbuf, float* __restrict__ hloc) {
    __shared__ float bc_s[TC * NBCDT];
    __shared__ float xc_s[TC][16];
    int tid = threadIdx.x;
    int s = tid & 15, ch = tid >> 4;
    int d0 = blockIdx.x * 16;
    int chunk = blockIdx.y;
    int dirb = blockIdx.z;
    int dir = dirb >> 1;
    size_t rbase = (size_t)dirb * LSEQ + (size_t)chunk * TC;  // dir*NTOK + b*LSEQ + t0
    const float* bsrc = bcdt + rbase * NBCDT;
    for (int i = tid; i < TC * NBCDT; i += 256) bc_s[i] = bsrc[i];
    for (int i = tid; i < TC * 16; i += 256) {
        int t = i >> 4, c2 = i & 15;
        xc_s[t][c2] = xc[(rbase + t) * DINNER + d0 + c2];
    }
    __syncthreads();
    int d = d0 + ch;
    const float* dtw  = dir ? b_dtw  : f_dtw;
    const float* dtb  = dir ? b_dtb  : f_dtb;
    const float* Alog = dir ? b_Alog : f_Alog;
    float al = fminf(fmaxf(Alog[d * NSTATE + s], -6.f), 6.f);
    float A_s = -expf(al);
    float dtw_d = dtw[d], dtb_d = dtb[d];
    float h = 0.f, P = 1.f;
    for (int t = 0; t < TC; t++) {
        float dt_raw = bc_s[t * NBCDT];
        float Bv = bc_s[t * NBCDT + 1 + s];
        float xv = xc_s[t][ch];
        float u = fmaf(dt_raw, dtw_d, dtb_d);
        float dt = fmaxf(u, 0.f) + log1pf(expf(-fabsf(u)));
        float a = expf(dt * A_s);
        h = clip1e4(fmaf(a, h, dt * Bv * xv));
        P *= a;
    }
    size_t idx = ((size_t)chunk * 4 + dirb) * (DINNER * NSTATE) + (size_t)d0 * 16 + tid;
    Pbuf[idx] = P;
    hloc[idx] = h;
}

// ---------------------------------------------------------------------------
// Kernel 5b: phase 2 -- stitch chunk boundary states (16 sequential steps).
// 98304 lanes, fully coalesced per step.
// ---------------------------------------------------------------------------
__global__ void scan_p2(const float* __restrict__ Pbuf, const float* __restrict__ hloc,
                        float* __restrict__ hin) {
    int i = blockIdx.x * 256 + threadIdx.x;   // [0, 4*DINNER*NSTATE)
    float h = 0.f;
    const int stride = 4 * DINNER * NSTATE;   // 98304
    for (int c = 0; c < NCHUNK; c++) {
        size_t idx = (size_t)c * stride + i;
        hin[idx] = h;
        h = clip1e4(fmaf(Pbuf[idx], h, hloc[idx]));
    }
}

// ---------------------------------------------------------------------------
// Kernel 5c: phase 3 -- re-run recurrence per chunk from stitched h_in,
// reduce over states, apply gate, write yv (coalesced via LDS).
// ---------------------------------------------------------------------------
__global__ __launch_bounds__(256)
void scan_p3(const float* __restrict__ xc, const float* __restrict__ bcdt,
             const float* __restrict__ sz, const float* __restrict__ hin,
             const float* __restrict__ f_dtw, const float* __restrict__ f_dtb,
             const float* __restrict__ f_Alog, const float* __restrict__ f_D,
             const float* __restrict__ b_dtw, const float* __restrict__ b_dtb,
             const float* __restrict__ b_Alog, const float* __restrict__ b_D,
             float* __restrict__ yv) {
    __shared__ float bc_s[TC * NBCDT];
    __shared__ float xc_s[TC][16];
    __shared__ float sz_s[TC][16];
    __shared__ float y_s[TC][16];
    int tid = threadIdx.x;
    int s = tid & 15, ch = tid >> 4;
    int d0 = blockIdx.x * 16;
    int chunk = blockIdx.y;
    int dirb = blockIdx.z;
    int dir = dirb >> 1, b = dirb & 1;
    int t0 = chunk * TC;
    size_t rbase = (size_t)dirb * LSEQ + (size_t)t0;
    const float* bsrc = bcdt + rbase * NBCDT;
    for (int i = tid; i < TC * NBCDT; i += 256) bc_s[i] = bsrc[i];
    for (int i = tid; i < TC * 16; i += 256) {
        int t = i >> 4, c2 = i & 15;
        xc_s[t][c2] = xc[(rbase + t) * DINNER + d0 + c2];
        int tt = t0 + t;
        int l = dir ? (LSEQ - 1 - tt) : tt;
        sz_s[t][c2] = sz[((size_t)dir * NTOK + (size_t)b * LSEQ + l) * DINNER + d0 + c2];
    }
    __syncthreads();
    int d = d0 + ch;
    const float* dtw  = dir ? b_dtw  : f_dtw;
    const float* dtb  = dir ? b_dtb  : f_dtb;
    const float* Alog = dir ? b_Alog : f_Alog;
    const float* Dp   = dir ? b_D    : f_D;
    float al = fminf(fmaxf(Alog[d * NSTATE + s], -6.f), 6.f);
    float A_s = -expf(al);
    float dtw_d = dtw[d], dtb_d = dtb[d], D_d = Dp[d];
    float h = hin[((size_t)chunk * 4 + dirb) * (DINNER * NSTATE) + (size_t)d0 * 16 + tid];
    for (int t = 0; t < TC; t++) {
        float dt_raw = bc_s[t * NBCDT];
        float Bv = bc_s[t * NBCDT + 1 + s];
        float Cv = bc_s[t * NBCDT + 1 + NSTATE + s];
        float xv = xc_s[t][ch];
        float u = fmaf(dt_raw, dtw_d, dtb_d);
        float dt = fmaxf(u, 0.f) + log1pf(expf(-fabsf(u)));
        float a = expf(dt * A_s);
        h = clip1e4(fmaf(a, h, dt * Bv * xv));
        float p = h * Cv;
        p += __shfl_xor(p, 1, 16);
        p += __shfl_xor(p, 2, 16);
        p += __shfl_xor(p, 4, 16);
        p += __shfl_xor(p, 8, 16);
        if (s == 0) y_s[t][ch] = (p + xv * D_d) * sz_s[t][ch];
    }
    __syncthreads();
    for (int i = tid; i < TC * 16; i += 256) {
        int t = i >> 4, c2 = i & 15;
        yv[(rbase + t) * DINNER + d0 + c2] = y_s[t][c2];
    }
}

// ---------------------------------------------------------------------------
// Kernel 6: output GEMM + blend + residual.
// ---------------------------------------------------------------------------
__global__ __launch_bounds__(256)
void gemm_out(const float* __restrict__ yv,
              const float* __restrict__ f_outw,   // [1536,768]
              const float* __restrict__ b_outw,
              const float* __restrict__ x,
              const float* __restrict__ alpha,
              float* __restrict__ out) {
    __shared__ float As[TK][64 + 1];
    __shared__ float Bs[TK][64 + 1];
    float a_blend = 1.f / (1.f + expf(-alpha[0]));
    int bm = blockIdx.y * 64;
    int bn = blockIdx.x * 64;
    int tid = threadIdx.x;
    int tx = tid & 15, ty = tid >> 4;
    float acc[4][4] = {};
    for (int k0 = 0; k0 < 2 * DINNER; k0 += TK) {
        #pragma unroll
        for (int i = 0; i < 4; i++) {
            int idx = tid + i * 256;
            int m = idx >> 4, k = idx & 15;
            int row = bm + m;
            int bb = row >> 11;
            int l = row & 2047;
            int gk = k0 + k;
            float v;
            if (gk < DINNER) {
                v = yv[(size_t)row * DINNER + gk];
            } else {
                size_t r2 = (size_t)NTOK + (size_t)bb * LSEQ + (LSEQ - 1 - l);
                v = yv[r2 * DINNER + (gk - DINNER)];
            }
            As[k][m] = v;
        }
        #pragma unroll
        for (int i = 0; i < 4; i++) {
            int idx = tid + i * 256;
            int k = idx >> 6, n = idx & 63;
            int gk = k0 + k;
            int gn = bn + n;
            float v;
            if (gk < DINNER) v = a_blend * f_outw[(size_t)gk * DMODEL + gn];
            else             v = (1.f - a_blend) * b_outw[(size_t)(gk - DINNER) * DMODEL + gn];
            Bs[k][n] = v;
        }
        __syncthreads();
        #pragma unroll
        for (int k = 0; k < TK; k++) {
            float a[4], b[4];
            #pragma unroll
            for (int i = 0; i < 4; i++) a[i] = As[k][ty * 4 + i];
            #pragma unroll
            for (int j = 0; j < 4; j++) b[j] = Bs[k][tx * 4 + j];
            #pragma unroll
            for (int i = 0; i < 4; i++)
                #pragma unroll
                for (int j = 0; j < 4; j++)
                    acc[i][j] = fmaf(a[i], b[j], acc[i][j]);
        }
        __syncthreads();
    }
    #pragma unroll
    for (int i = 0; i < 4; i++) {
        int row = bm + ty * 4 + i;
        #pragma unroll
        for (int j = 0; j < 4; j++) {
            int gn = bn + tx * 4 + j;
            out[(size_t)row * DMODEL + gn] = acc[i][j] + x[(size_t)row * DMODEL + gn];
        }
    }
}

// ---------------------------------------------------------------------------
extern "C" void kernel_launch(void* const* d_in, const int* in_sizes, int n_in,
                              void* d_out, int out_size, void* d_ws, size_t ws_size,
                              hipStream_t stream) {
    const float* x     = (const float*)d_in[0];
    const float* ln_g  = (const float*)d_in[1];
    const float* ln_b  = (const float*)d_in[2];
    const float* alpha = (const float*)d_in[3];
    const float* f_inw  = (const float*)d_in[4];
    const float* f_cw   = (const float*)d_in[5];
    const float* f_cb   = (const float*)d_in[6];
    const float* f_xw   = (const float*)d_in[7];
    const float* f_dtw  = (const float*)d_in[8];
    const float* f_dtb  = (const float*)d_in[9];
    const float* f_Alog = (const float*)d_in[10];
    const float* f_D    = (const float*)d_in[11];
    const float* f_outw = (const float*)d_in[12];
    const float* b_inw  = (const float*)d_in[13];
    const float* b_cw   = (const float*)d_in[14];
    const float* b_cb   = (const float*)d_in[15];
    const float* b_xw   = (const float*)d_in[16];
    const float* b_dtw  = (const float*)d_in[17];
    const float* b_dtb  = (const float*)d_in[18];
    const float* b_Alog = (const float*)d_in[19];
    const float* b_D    = (const float*)d_in[20];
    const float* b_outw = (const float*)d_in[21];
    float* out = (float*)d_out;

    // Workspace layout (floats):
    float* ws = (float*)d_ws;
    const size_t xn_sz = (size_t)NTOK * DMODEL;        //  3,145,728
    const size_t big   = (size_t)2 * NTOK * DINNER;    // 12,582,912
    float* xn   = ws;                 // dead after gemm_xz -> reused for Pbuf/hloc
    float* xi   = xn + xn_sz;         // dead after conv -> reused as yv
    float* sz   = xi + big;
    float* xc   = sz + big;
    float* bcdt = xc + big;           // 270,336 floats
    float* hin  = bcdt + (size_t)2 * NTOK * NBCDT;   // SUMSZ floats
    float* Pbuf = xn;                 // SUMSZ
    float* hloc = xn + SUMSZ;         // SUMSZ  (2*SUMSZ == xn_sz exactly)
    float* yv   = xi;

    // 1. LayerNorm
    ln_kernel<<<NTOK, 256, 0, stream>>>(x, ln_g, ln_b, xn);
    // 2. xz GEMM (both dirs)
    {
        dim3 grid(6144 / 64, 4096 / 64);
        gemm_xz<<<grid, 256, 0, stream>>>(xn, f_inw, b_inw, xi, sz);
    }
    // 3. conv + silu
    {
        size_t total = (size_t)2 * NTOK * DINNER;
        conv_silu<<<(total + 255) / 256, 256, 0, stream>>>(xi, f_cw, f_cb, b_cw, b_cb, xc);
    }
    // 4. bcdt skinny GEMM
    bcdt_gemm<<<(2 * NTOK) / 64, 256, 0, stream>>>(xc, f_xw, b_xw, bcdt);
    // 5. chunked scan
    {
        dim3 grid1(DINNER / 16, NCHUNK, 4);
        scan_p1<<<grid1, 256, 0, stream>>>(xc, bcdt,
                                           f_dtw, f_dtb, f_Alog,
                                           b_dtw, b_dtb, b_Alog, Pbuf, hloc);
        scan_p2<<<(4 * DINNER * NSTATE) / 256, 256, 0, stream>>>(Pbuf, hloc, hin);
        scan_p3<<<grid1, 256, 0, stream>>>(xc, bcdt, sz, hin,
                                           f_dtw, f_dtb, f_Alog, f_D,
                                           b_dtw, b_dtb, b_Alog, b_D, yv);
    }
    // 6. out GEMM + blend + residual
    {
        dim3 grid(DMODEL / 64, NTOK / 64);
        gemm_out<<<grid, 256, 0, stream>>>(yv, f_outw, b_outw, x, alpha, out);
    }
}

// Round 3
// 2025.964 us; speedup vs baseline: 1.6646x; 1.5408x over previous
//
#include <hip/hip_runtime.h>
#include <cstddef>
#include <cstdint>

// Problem constants (fixed by reference)
#define DMODEL 768
#define DINNER 1536
#define NSTATE 16
#define LSEQ   2048
#define NB     2
#define NTOK   (NB*LSEQ)        // 4096 tokens
#define NBCDT  33               // 1 + 2*16

// Chunked scan parameters
#define TC     128              // timesteps per chunk
#define NCHUNK (LSEQ/TC)        // 16
#define SUMSZ  (NCHUNK*4*DINNER*NSTATE)   // 1,572,864 floats

// MFMA GEMM params
#define LDK 72                  // padded LDS stride in bf16 elems (64 + 8)

typedef __bf16 bf16x8 __attribute__((ext_vector_type(8)));
typedef float  floatx4 __attribute__((ext_vector_type(4)));
typedef unsigned short us8 __attribute__((ext_vector_type(8)));

__device__ __forceinline__ float silu_f(float x) { return x / (1.f + expf(-x)); }
__device__ __forceinline__ float clip1e4(float x) { return fminf(fmaxf(x, -1e4f), 1e4f); }
__device__ __forceinline__ unsigned short f2bf(float f) {   // RNE float->bf16 bits
    unsigned int u = __float_as_uint(f);
    unsigned int r = u + 0x7fffu + ((u >> 16) & 1u);
    return (unsigned short)(r >> 16);
}

// ---------------------------------------------------------------------------
// Kernel 1: LayerNorm -> bf16 output. one block per token row.
// ---------------------------------------------------------------------------
__global__ void ln_kernel(const float* __restrict__ x,
                          const float* __restrict__ g,
                          const float* __restrict__ be,
                          unsigned short* __restrict__ xnb) {
    int row = blockIdx.x;
    int tid = threadIdx.x;
    const float* xr = x + (size_t)row * DMODEL;
    float s = 0.f, ss = 0.f;
    for (int i = tid; i < DMODEL; i += 256) {
        float v = xr[i];
        s += v; ss += v * v;
    }
    for (int o = 32; o >= 1; o >>= 1) {
        s  += __shfl_xor(s,  o, 64);
        ss += __shfl_xor(ss, o, 64);
    }
    __shared__ float sS[4], sSS[4];
    int w = tid >> 6;
    if ((tid & 63) == 0) { sS[w] = s; sSS[w] = ss; }
    __syncthreads();
    s  = sS[0] + sS[1] + sS[2] + sS[3];
    ss = sSS[0] + sSS[1] + sSS[2] + sSS[3];
    float mu = s / DMODEL;
    float var = ss / DMODEL - mu * mu;
    float rstd = rsqrtf(var + 1e-5f);
    unsigned short* xo = xnb + (size_t)row * DMODEL;
    for (int i = tid; i < DMODEL; i += 256)
        xo[i] = f2bf((xr[i] - mu) * rstd * g[i] + be[i]);
}

// ---------------------------------------------------------------------------
// Kernel 2a: transpose-cast in-proj weights: inwT[n][k] (bf16), n in [0,6144)
// src: n<3072 -> f_inw[k][n], else b_inw[k][n-3072].  32x32 LDS-tiled.
// ---------------------------------------------------------------------------
__global__ __launch_bounds__(256)
void cast_inwT(const float* __restrict__ fw, const float* __restrict__ bw,
               unsigned short* __restrict__ wT) {
    __shared__ float t[32][33];
    int n0 = blockIdx.x * 32;     // 192 blocks
    int k0 = blockIdx.y * 32;     // 24 blocks
    int tid = threadIdx.x;
    int lr = tid >> 5, lc = tid & 31;
    const float* w = (n0 >= 3072) ? bw : fw;
    int nb = (n0 >= 3072) ? (n0 - 3072) : n0;
    #pragma unroll
    for (int r = 0; r < 4; r++)
        t[r * 8 + lr][lc] = w[(size_t)(k0 + r * 8 + lr) * 3072 + nb + lc];
    __syncthreads();
    #pragma unroll
    for (int r = 0; r < 4; r++)
        wT[(size_t)(n0 + r * 8 + lr) * DMODEL + k0 + lc] = f2bf(t[lc][r * 8 + lr]);
}

// ---------------------------------------------------------------------------
// Kernel 2b: transpose-cast out-proj weights with blend scale folded in.
// outwT[n][k] (bf16), n in [0,768), k in [0,3072):
//   k<1536 -> a*f_outw[k][n] ; else (1-a)*b_outw[k-1536][n]
// ---------------------------------------------------------------------------
__global__ __launch_bounds__(256)
void cast_outwT(const float* __restrict__ fw, const float* __restrict__ bw,
                const float* __restrict__ alpha, unsigned short* __restrict__ wT) {
    __shared__ float t[32][33];
    float a = 1.f / (1.f + expf(-alpha[0]));
    int n0 = blockIdx.x * 32;     // 24 blocks
    int k0 = blockIdx.y * 32;     // 96 blocks
    int tid = threadIdx.x;
    int lr = tid >> 5, lc = tid & 31;
    const float* w = (k0 >= DINNER) ? bw : fw;
    float sc = (k0 >= DINNER) ? (1.f - a) : a;
    int kb = (k0 >= DINNER) ? (k0 - DINNER) : k0;
    #pragma unroll
    for (int r = 0; r < 4; r++)
        t[r * 8 + lr][lc] = w[(size_t)(kb + r * 8 + lr) * DMODEL + n0 + lc];
    __syncthreads();
    #pragma unroll
    for (int r = 0; r < 4; r++)
        wT[(size_t)(n0 + r * 8 + lr) * 3072 + k0 + lc] = f2bf(sc * t[lc][r * 8 + lr]);
}

// ---------------------------------------------------------------------------
// Kernel 3: xz GEMM via MFMA bf16.  M=4096, N=6144, K=768.
// A = xnb [4096][768], B^T = inwT [6144][768].  128x128 tile, BK=64.
// Epilogue: cols [0,1536)+dir -> xi (fp32), cols [1536,3072)+dir -> silu -> sz.
// ---------------------------------------------------------------------------
__global__ __launch_bounds__(256)
void gemm_xz_mfma(const unsigned short* __restrict__ xnb,
                  const unsigned short* __restrict__ inwT,
                  float* __restrict__ xi, float* __restrict__ sz) {
    __shared__ unsigned short Asm[128 * LDK];
    __shared__ unsigned short Bsm[128 * LDK];
    int tid = threadIdx.x;
    int bm = blockIdx.y * 128;
    int bn = blockIdx.x * 128;
    int wave = tid >> 6, lane = tid & 63;
    int wm = (wave & 1) * 64, wn = (wave >> 1) * 64;
    int col15 = lane & 15, quad = lane >> 4;
    floatx4 acc[4][4];
    #pragma unroll
    for (int i = 0; i < 4; i++)
        #pragma unroll
        for (int j = 0; j < 4; j++)
            acc[i][j] = (floatx4){0.f, 0.f, 0.f, 0.f};

    for (int k0 = 0; k0 < DMODEL; k0 += 64) {
        #pragma unroll
        for (int i = 0; i < 4; i++) {
            int c = tid + i * 256;          // 1024 chunks of 8 bf16
            int m = c >> 3, kk = c & 7;
            *(us8*)(&Asm[m * LDK + kk * 8]) =
                *(const us8*)(&xnb[(size_t)(bm + m) * DMODEL + k0 + kk * 8]);
            *(us8*)(&Bsm[m * LDK + kk * 8]) =
                *(const us8*)(&inwT[(size_t)(bn + m) * DMODEL + k0 + kk * 8]);
        }
        __syncthreads();
        #pragma unroll
        for (int k2 = 0; k2 < 2; k2++) {
            bf16x8 af[4], bf_[4];
            #pragma unroll
            for (int mt = 0; mt < 4; mt++)
                af[mt] = *(const bf16x8*)(&Asm[(wm + mt * 16 + col15) * LDK + k2 * 32 + quad * 8]);
            #pragma unroll
            for (int nt = 0; nt < 4; nt++)
                bf_[nt] = *(const bf16x8*)(&Bsm[(wn + nt * 16 + col15) * LDK + k2 * 32 + quad * 8]);
            #pragma unroll
            for (int mt = 0; mt < 4; mt++)
                #pragma unroll
                for (int nt = 0; nt < 4; nt++)
                    acc[mt][nt] = __builtin_amdgcn_mfma_f32_16x16x32_bf16(
                        af[mt], bf_[nt], acc[mt][nt], 0, 0, 0);
        }
        __syncthreads();
    }
    #pragma unroll
    for (int mt = 0; mt < 4; mt++) {
        #pragma unroll
        for (int nt = 0; nt < 4; nt++) {
            #pragma unroll
            for (int r = 0; r < 4; r++) {
                int row = bm + wm + mt * 16 + quad * 4 + r;
                int gn  = bn + wn + nt * 16 + col15;
                float v = acc[mt][nt][r];
                int dir = (gn >= 3072) ? 1 : 0;
                int cc = gn - dir * 3072;
                size_t base = ((size_t)dir * NTOK + row) * DINNER;
                if (cc < DINNER) xi[base + cc] = v;
                else             sz[base + cc - DINNER] = silu_f(v);
            }
        }
    }
}

// ---------------------------------------------------------------------------
// Kernel 4: depthwise causal conv (k=4) + bias + SiLU. (unchanged, fp32)
// ---------------------------------------------------------------------------
__global__ void conv_silu(const float* __restrict__ xi,
                          const float* __restrict__ f_cw, const float* __restrict__ f_cb,
                          const float* __restrict__ b_cw, const float* __restrict__ b_cb,
                          float* __restrict__ xc) {
    size_t gid = (size_t)blockIdx.x * 256 + threadIdx.x;
    const size_t total = (size_t)2 * NTOK * DINNER;
    if (gid >= total) return;
    int d = (int)(gid % DINNER);
    size_t r = gid / DINNER;          // (dir*2+b)*LSEQ + t
    int t = (int)(r % LSEQ);
    int b = (int)((r / LSEQ) % NB);
    int dir = (int)(r / (LSEQ * NB));
    const float* cw = dir ? b_cw : f_cw;
    const float* cb = dir ? b_cb : f_cb;
    float acc = cb[d];
    size_t xib = ((size_t)dir * NTOK + (size_t)b * LSEQ) * DINNER;
    #pragma unroll
    for (int k = 0; k < 4; k++) {
        int u = t - 3 + k;
        if (u < 0) continue;
        int l = dir ? (LSEQ - 1 - u) : u;
        acc = fmaf(cw[d * 4 + k], xi[xib + (size_t)l * DINNER + d], acc);
    }
    xc[gid] = silu_f(acc);
}

// ---------------------------------------------------------------------------
// Kernel 5: bcdt = xc @ xw  -- tiled skinny GEMM. (unchanged, fp32)
// ---------------------------------------------------------------------------
__global__ __launch_bounds__(256)
void bcdt_gemm(const float* __restrict__ xc,
               const float* __restrict__ f_xw,
               const float* __restrict__ b_xw,
               float* __restrict__ bcdt) {
    __shared__ float As[64][33];
    __shared__ float Ws[32 * 33];
    int r0 = blockIdx.x * 64;
    const float* xw = (r0 >= NTOK) ? b_xw : f_xw;
    int tid = threadIdx.x;
    int m = tid >> 2, jq = tid & 3;
    float acc[9] = {};
    for (int k0 = 0; k0 < DINNER; k0 += 32) {
        for (int i = tid; i < 64 * 32; i += 256) {
            int mm = i >> 5, k = i & 31;
            As[mm][k] = xc[((size_t)r0 + mm) * DINNER + k0 + k];
        }
        for (int i = tid; i < 32 * 33; i += 256)
            Ws[i] = xw[(size_t)k0 * 33 + i];
        __syncthreads();
        #pragma unroll 8
        for (int k = 0; k < 32; k++) {
            float a = As[m][k];
            #pragma unroll
            for (int jj = 0; jj < 9; jj++) {
                int j = jq + jj * 4;
                if (j < 33) acc[jj] = fmaf(a, Ws[k * 33 + j], acc[jj]);
            }
        }
        __syncthreads();
    }
    #pragma unroll
    for (int jj = 0; jj < 9; jj++) {
        int j = jq + jj * 4;
        if (j < 33) bcdt[((size_t)r0 + m) * 33 + j] = acc[jj];
    }
}

// ---------------------------------------------------------------------------
// Kernel 6a: chunked scan phase 1 (unchanged)
// ---------------------------------------------------------------------------
__global__ __launch_bounds__(256)
void scan_p1(const float* __restrict__ xc, const float* __restrict__ bcdt,
             const float* __restrict__ f_dtw, const float* __restrict__ f_dtb,
             const float* __restrict__ f_Alog,
             const float* __restrict__ b_dtw, const float* __restrict__ b_dtb,
             const float* __restrict__ b_Alog,
             float* __restrict__ Pbuf, float* __restrict__ hloc) {
    __shared__ float bc_s[TC * NBCDT];
    __shared__ float xc_s[TC][16];
    int tid = threadIdx.x;
    int s = tid & 15, ch = tid >> 4;
    int d0 = blockIdx.x * 16;
    int chunk = blockIdx.y;
    int dirb = blockIdx.z;
    int dir = dirb >> 1;
    size_t rbase = (size_t)dirb * LSEQ + (size_t)chunk * TC;
    const float* bsrc = bcdt + rbase * NBCDT;
    for (int i = tid; i < TC * NBCDT; i += 256) bc_s[i] = bsrc[i];
    for (int i = tid; i < TC * 16; i += 256) {
        int t = i >> 4, c2 = i & 15;
        xc_s[t][c2] = xc[(rbase + t) * DINNER + d0 + c2];
    }
    __syncthreads();
    int d = d0 + ch;
    const float* dtw  = dir ? b_dtw  : f_dtw;
    const float* dtb  = dir ? b_dtb  : f_dtb;
    const float* Alog = dir ? b_Alog : f_Alog;
    float al = fminf(fmaxf(Alog[d * NSTATE + s], -6.f), 6.f);
    float A_s = -expf(al);
    float dtw_d = dtw[d], dtb_d = dtb[d];
    float h = 0.f, P = 1.f;
    for (int t = 0; t < TC; t++) {
        float dt_raw = bc_s[t * NBCDT];
        float Bv = bc_s[t * NBCDT + 1 + s];
        float xv = xc_s[t][ch];
        float u = fmaf(dt_raw, dtw_d, dtb_d);
        float dt = fmaxf(u, 0.f) + log1pf(expf(-fabsf(u)));
        float a = expf(dt * A_s);
        h = clip1e4(fmaf(a, h, dt * Bv * xv));
        P *= a;
    }
    size_t idx = ((size_t)chunk * 4 + dirb) * (DINNER * NSTATE) + (size_t)d0 * 16 + tid;
    Pbuf[idx] = P;
    hloc[idx] = h;
}

// ---------------------------------------------------------------------------
// Kernel 6b: phase 2 -- stitch chunk boundary states (unchanged)
// ---------------------------------------------------------------------------
__global__ void scan_p2(const float* __restrict__ Pbuf, const float* __restrict__ hloc,
                        float* __restrict__ hin) {
    int i = blockIdx.x * 256 + threadIdx.x;
    float h = 0.f;
    const int stride = 4 * DINNER * NSTATE;
    for (int c = 0; c < NCHUNK; c++) {
        size_t idx = (size_t)c * stride + i;
        hin[idx] = h;
        h = clip1e4(fmaf(Pbuf[idx], h, hloc[idx]));
    }
}

// ---------------------------------------------------------------------------
// Kernel 6c: phase 3 -- re-run from stitched h_in; write bf16 yvb [4096][3072]
// with fwd at cols [0,1536) (row = token) and bwd at cols [1536,3072)
// (row = flipped token), so gemm_out needs no flip logic.
// ---------------------------------------------------------------------------
__global__ __launch_bounds__(256)
void scan_p3(const float* __restrict__ xc, const float* __restrict__ bcdt,
             const float* __restrict__ sz, const float* __restrict__ hin,
             const float* __restrict__ f_dtw, const float* __restrict__ f_dtb,
             const float* __restrict__ f_Alog, const float* __restrict__ f_D,
             const float* __restrict__ b_dtw, const float* __restrict__ b_dtb,
             const float* __restrict__ b_Alog, const float* __restrict__ b_D,
             unsigned short* __restrict__ yvb) {
    __shared__ float bc_s[TC * NBCDT];
    __shared__ float xc_s[TC][16];
    __shared__ float sz_s[TC][16];
    __shared__ float y_s[TC][16];
    int tid = threadIdx.x;
    int s = tid & 15, ch = tid >> 4;
    int d0 = blockIdx.x * 16;
    int chunk = blockIdx.y;
    int dirb = blockIdx.z;
    int dir = dirb >> 1, b = dirb & 1;
    int t0 = chunk * TC;
    size_t rbase = (size_t)dirb * LSEQ + (size_t)t0;
    const float* bsrc = bcdt + rbase * NBCDT;
    for (int i = tid; i < TC * NBCDT; i += 256) bc_s[i] = bsrc[i];
    for (int i = tid; i < TC * 16; i += 256) {
        int t = i >> 4, c2 = i & 15;
        xc_s[t][c2] = xc[(rbase + t) * DINNER + d0 + c2];
        int tt = t0 + t;
        int l = dir ? (LSEQ - 1 - tt) : tt;
        sz_s[t][c2] = sz[((size_t)dir * NTOK + (size_t)b * LSEQ + l) * DINNER + d0 + c2];
    }
    __syncthreads();
    int d = d0 + ch;
    const float* dtw  = dir ? b_dtw  : f_dtw;
    const float* dtb  = dir ? b_dtb  : f_dtb;
    const float* Alog = dir ? b_Alog : f_Alog;
    const float* Dp   = dir ? b_D    : f_D;
    float al = fminf(fmaxf(Alog[d * NSTATE + s], -6.f), 6.f);
    float A_s = -expf(al);
    float dtw_d = dtw[d], dtb_d = dtb[d], D_d = Dp[d];
    float h = hin[((size_t)chunk * 4 + dirb) * (DINNER * NSTATE) + (size_t)d0 * 16 + tid];
    for (int t = 0; t < TC; t++) {
        float dt_raw = bc_s[t * NBCDT];
        float Bv = bc_s[t * NBCDT + 1 + s];
        float Cv = bc_s[t * NBCDT + 1 + NSTATE + s];
        float xv = xc_s[t][ch];
        float u = fmaf(dt_raw, dtw_d, dtb_d);
        float dt = fmaxf(u, 0.f) + log1pf(expf(-fabsf(u)));
        float a = expf(dt * A_s);
        h = clip1e4(fmaf(a, h, dt * Bv * xv));
        float p = h * Cv;
        p += __shfl_xor(p, 1, 16);
        p += __shfl_xor(p, 2, 16);
        p += __shfl_xor(p, 4, 16);
        p += __shfl_xor(p, 8, 16);
        if (s == 0) y_s[t][ch] = (p + xv * D_d) * sz_s[t][ch];
    }
    __syncthreads();
    for (int i = tid; i < TC * 16; i += 256) {
        int t = i >> 4, c2 = i & 15;
        int tt = t0 + t;
        int l = dir ? (LSEQ - 1 - tt) : tt;
        int row = b * LSEQ + l;
        yvb[(size_t)row * 3072 + dir * DINNER + d0 + c2] = f2bf(y_s[t][c2]);
    }
}

// ---------------------------------------------------------------------------
// Kernel 7: output GEMM via MFMA bf16 + residual.
// M=4096, N=768, K=3072.  A = yvb, B^T = outwT (blend pre-scaled).
// 128x64 tile, 4 waves (2x2), wave = 64x32 (4x2 MFMA tiles), BK=64.
// ---------------------------------------------------------------------------
__global__ __launch_bounds__(256)
void gemm_out_mfma(const unsigned short* __restrict__ yvb,
                   const unsigned short* __restrict__ outwT,
                   const float* __restrict__ x,
                   float* __restrict__ out) {
    __shared__ unsigned short Asm[128 * LDK];
    __shared__ unsigned short Bsm[64 * LDK];
    int tid = threadIdx.x;
    int bm = blockIdx.y * 128;
    int bn = blockIdx.x * 64;
    int wave = tid >> 6, lane = tid & 63;
    int wm = (wave & 1) * 64, wn = (wave >> 1) * 32;
    int col15 = lane & 15, quad = lane >> 4;
    floatx4 acc[4][2];
    #pragma unroll
    for (int i = 0; i < 4; i++)
        #pragma unroll
        for (int j = 0; j < 2; j++)
            acc[i][j] = (floatx4){0.f, 0.f, 0.f, 0.f};

    for (int k0 = 0; k0 < 2 * DINNER; k0 += 64) {
        #pragma unroll
        for (int i = 0; i < 4; i++) {
            int c = tid + i * 256;
            int m = c >> 3, kk = c & 7;
            *(us8*)(&Asm[m * LDK + kk * 8]) =
                *(const us8*)(&yvb[(size_t)(bm + m) * 3072 + k0 + kk * 8]);
        }
        #pragma unroll
        for (int i = 0; i < 2; i++) {
            int c = tid + i * 256;
            int n = c >> 3, kk = c & 7;
            *(us8*)(&Bsm[n * LDK + kk * 8]) =
                *(const us8*)(&outwT[(size_t)(bn + n) * 3072 + k0 + kk * 8]);
        }
        __syncthreads();
        #pragma unroll
        for (int k2 = 0; k2 < 2; k2++) {
            bf16x8 af[4], bf_[2];
            #pragma unroll
            for (int mt = 0; mt < 4; mt++)
                af[mt] = *(const bf16x8*)(&Asm[(wm + mt * 16 + col15) * LDK + k2 * 32 + quad * 8]);
            #pragma unroll
            for (int nt = 0; nt < 2; nt++)
                bf_[nt] = *(const bf16x8*)(&Bsm[(wn + nt * 16 + col15) * LDK + k2 * 32 + quad * 8]);
            #pragma unroll
            for (int mt = 0; mt < 4; mt++)
                #pragma unroll
                for (int nt = 0; nt < 2; nt++)
                    acc[mt][nt] = __builtin_amdgcn_mfma_f32_16x16x32_bf16(
                        af[mt], bf_[nt], acc[mt][nt], 0, 0, 0);
        }
        __syncthreads();
    }
    #pragma unroll
    for (int mt = 0; mt < 4; mt++) {
        #pragma unroll
        for (int nt = 0; nt < 2; nt++) {
            #pragma unroll
            for (int r = 0; r < 4; r++) {
                int row = bm + wm + mt * 16 + quad * 4 + r;
                int gn  = bn + wn + nt * 16 + col15;
                out[(size_t)row * DMODEL + gn] = acc[mt][nt][r] + x[(size_t)row * DMODEL + gn];
            }
        }
    }
}

// ---------------------------------------------------------------------------
extern "C" void kernel_launch(void* const* d_in, const int* in_sizes, int n_in,
                              void* d_out, int out_size, void* d_ws, size_t ws_size,
                              hipStream_t stream) {
    const float* x     = (const float*)d_in[0];
    const float* ln_g  = (const float*)d_in[1];
    const float* ln_b  = (const float*)d_in[2];
    const float* alpha = (const float*)d_in[3];
    const float* f_inw  = (const float*)d_in[4];
    const float* f_cw   = (const float*)d_in[5];
    const float* f_cb   = (const float*)d_in[6];
    const float* f_xw   = (const float*)d_in[7];
    const float* f_dtw  = (const float*)d_in[8];
    const float* f_dtb  = (const float*)d_in[9];
    const float* f_Alog = (const float*)d_in[10];
    const float* f_D    = (const float*)d_in[11];
    const float* f_outw = (const float*)d_in[12];
    const float* b_inw  = (const float*)d_in[13];
    const float* b_cw   = (const float*)d_in[14];
    const float* b_cb   = (const float*)d_in[15];
    const float* b_xw   = (const float*)d_in[16];
    const float* b_dtw  = (const float*)d_in[17];
    const float* b_dtb  = (const float*)d_in[18];
    const float* b_Alog = (const float*)d_in[19];
    const float* b_D    = (const float*)d_in[20];
    const float* b_outw = (const float*)d_in[21];
    float* out = (float*)d_out;

    // Workspace layout (float offsets; all regions 16B-aligned):
    float* ws = (float*)d_ws;
    const size_t big = (size_t)2 * NTOK * DINNER;       // 12,582,912
    float* r_xnb  = ws;                                  // 1,572,864 fl (xnb bf16) -> Pbuf
    float* r_inwT = r_xnb + 1572864;                     // 2,359,296 fl (inwT bf16) -> hloc
    float* r_outwT= r_inwT + 2359296;                    // 1,179,648 fl (outwT bf16)
    float* xi     = r_outwT + 1179648;                   // big (fp32) -> yvb (bf16, 6.29M fl)
    float* sz     = xi + big;                            // big
    float* xc     = sz + big;                            // big
    float* bcdt   = xc + big;                            // 270,336
    float* hin    = bcdt + (size_t)2 * NTOK * NBCDT;     // 1,572,864

    unsigned short* xnb   = (unsigned short*)r_xnb;
    unsigned short* inwT  = (unsigned short*)r_inwT;
    unsigned short* outwT = (unsigned short*)r_outwT;
    unsigned short* yvb   = (unsigned short*)xi;         // alias: xi dead after conv
    float* Pbuf = r_xnb;                                  // alias: xnb dead after gemm_xz
    float* hloc = r_inwT;                                 // alias: inwT dead after gemm_xz

    // 1. LayerNorm -> bf16
    ln_kernel<<<NTOK, 256, 0, stream>>>(x, ln_g, ln_b, xnb);
    // 2. weight transpose-casts
    {
        dim3 g1(6144 / 32, DMODEL / 32);
        cast_inwT<<<g1, 256, 0, stream>>>(f_inw, b_inw, inwT);
        dim3 g2(DMODEL / 32, 3072 / 32);
        cast_outwT<<<g2, 256, 0, stream>>>(f_outw, b_outw, alpha, outwT);
    }
    // 3. xz GEMM (MFMA)
    {
        dim3 grid(6144 / 128, NTOK / 128);
        gemm_xz_mfma<<<grid, 256, 0, stream>>>(xnb, inwT, xi, sz);
    }
    // 4. conv + silu
    {
        size_t total = (size_t)2 * NTOK * DINNER;
        conv_silu<<<(total + 255) / 256, 256, 0, stream>>>(xi, f_cw, f_cb, b_cw, b_cb, xc);
    }
    // 5. bcdt skinny GEMM
    bcdt_gemm<<<(2 * NTOK) / 64, 256, 0, stream>>>(xc, f_xw, b_xw, bcdt);
    // 6. chunked scan
    {
        dim3 grid1(DINNER / 16, NCHUNK, 4);
        scan_p1<<<grid1, 256, 0, stream>>>(xc, bcdt,
                                           f_dtw, f_dtb, f_Alog,
                                           b_dtw, b_dtb, b_Alog, Pbuf, hloc);
        scan_p2<<<(4 * DINNER * NSTATE) / 256, 256, 0, stream>>>(Pbuf, hloc, hin);
        scan_p3<<<grid1, 256, 0, stream>>>(xc, bcdt, sz, hin,
                                           f_dtw, f_dtb, f_Alog, f_D,
                                           b_dtw, b_dtb, b_Alog, b_D, yvb);
    }
    // 7. out GEMM (MFMA) + residual
    {
        dim3 grid(DMODEL / 64, NTOK / 128);
        gemm_out_mfma<<<grid, 256, 0, stream>>>(yvb, outwT, x, out);
    }
}

// Round 4
// 557.613 us; speedup vs baseline: 6.0479x; 3.6333x over previous
//
#include <hip/hip_runtime.h>
#include <cstddef>
#include <cstdint>

// Problem constants (fixed by reference)
#define DMODEL 768
#define DINNER 1536
#define NSTATE 16
#define LSEQ   2048
#define NB     2
#define NTOK   (NB*LSEQ)        // 4096 tokens
#define NBCDT  33               // 1 + 2*16

// Chunked scan parameters
#define TC     128              // timesteps per chunk
#define NCHUNK (LSEQ/TC)        // 16
#define KSPLIT 6                // bcdt split-K factor (1536/256)

// MFMA GEMM params
#define LDK 72                  // padded LDS stride in bf16 elems (64 + 8)

typedef __bf16 bf16x8 __attribute__((ext_vector_type(8)));
typedef float  floatx4 __attribute__((ext_vector_type(4)));
typedef unsigned short us8 __attribute__((ext_vector_type(8)));

__device__ __forceinline__ float silu_f(float x) { return x / (1.f + expf(-x)); }
__device__ __forceinline__ float clip1e4(float x) { return fminf(fmaxf(x, -1e4f), 1e4f); }
__device__ __forceinline__ unsigned short f2bf(float f) {   // RNE float->bf16 bits
    unsigned int u = __float_as_uint(f);
    unsigned int r = u + 0x7fffu + ((u >> 16) & 1u);
    return (unsigned short)(r >> 16);
}

// ---------------------------------------------------------------------------
// Kernel 1: LayerNorm -> bf16 output. one block per token row.
// ---------------------------------------------------------------------------
__global__ void ln_kernel(const float* __restrict__ x,
                          const float* __restrict__ g,
                          const float* __restrict__ be,
                          unsigned short* __restrict__ xnb) {
    int row = blockIdx.x;
    int tid = threadIdx.x;
    const float* xr = x + (size_t)row * DMODEL;
    float s = 0.f, ss = 0.f;
    for (int i = tid; i < DMODEL; i += 256) {
        float v = xr[i];
        s += v; ss += v * v;
    }
    for (int o = 32; o >= 1; o >>= 1) {
        s  += __shfl_xor(s,  o, 64);
        ss += __shfl_xor(ss, o, 64);
    }
    __shared__ float sS[4], sSS[4];
    int w = tid >> 6;
    if ((tid & 63) == 0) { sS[w] = s; sSS[w] = ss; }
    __syncthreads();
    s  = sS[0] + sS[1] + sS[2] + sS[3];
    ss = sSS[0] + sSS[1] + sSS[2] + sSS[3];
    float mu = s / DMODEL;
    float var = ss / DMODEL - mu * mu;
    float rstd = rsqrtf(var + 1e-5f);
    unsigned short* xo = xnb + (size_t)row * DMODEL;
    for (int i = tid; i < DMODEL; i += 256)
        xo[i] = f2bf((xr[i] - mu) * rstd * g[i] + be[i]);
}

// ---------------------------------------------------------------------------
// Kernel 2a: transpose-cast in-proj weights: inwT[n][k] (bf16), n in [0,6144)
// ---------------------------------------------------------------------------
__global__ __launch_bounds__(256)
void cast_inwT(const float* __restrict__ fw, const float* __restrict__ bw,
               unsigned short* __restrict__ wT) {
    __shared__ float t[32][33];
    int n0 = blockIdx.x * 32;     // 192 blocks
    int k0 = blockIdx.y * 32;     // 24 blocks
    int tid = threadIdx.x;
    int lr = tid >> 5, lc = tid & 31;
    const float* w = (n0 >= 3072) ? bw : fw;
    int nb = (n0 >= 3072) ? (n0 - 3072) : n0;
    #pragma unroll
    for (int r = 0; r < 4; r++)
        t[r * 8 + lr][lc] = w[(size_t)(k0 + r * 8 + lr) * 3072 + nb + lc];
    __syncthreads();
    #pragma unroll
    for (int r = 0; r < 4; r++)
        wT[(size_t)(n0 + r * 8 + lr) * DMODEL + k0 + lc] = f2bf(t[lc][r * 8 + lr]);
}

// ---------------------------------------------------------------------------
// Kernel 2b: transpose-cast out-proj weights with blend scale folded in.
// ---------------------------------------------------------------------------
__global__ __launch_bounds__(256)
void cast_outwT(const float* __restrict__ fw, const float* __restrict__ bw,
                const float* __restrict__ alpha, unsigned short* __restrict__ wT) {
    __shared__ float t[32][33];
    float a = 1.f / (1.f + expf(-alpha[0]));
    int n0 = blockIdx.x * 32;     // 24 blocks
    int k0 = blockIdx.y * 32;     // 96 blocks
    int tid = threadIdx.x;
    int lr = tid >> 5, lc = tid & 31;
    const float* w = (k0 >= DINNER) ? bw : fw;
    float sc = (k0 >= DINNER) ? (1.f - a) : a;
    int kb = (k0 >= DINNER) ? (k0 - DINNER) : k0;
    #pragma unroll
    for (int r = 0; r < 4; r++)
        t[r * 8 + lr][lc] = w[(size_t)(kb + r * 8 + lr) * DMODEL + n0 + lc];
    __syncthreads();
    #pragma unroll
    for (int r = 0; r < 4; r++)
        wT[(size_t)(n0 + r * 8 + lr) * 3072 + k0 + lc] = f2bf(sc * t[lc][r * 8 + lr]);
}

// ---------------------------------------------------------------------------
// Kernel 3: xz GEMM via MFMA bf16.  M=4096, N=6144, K=768.
// ---------------------------------------------------------------------------
__global__ __launch_bounds__(256)
void gemm_xz_mfma(const unsigned short* __restrict__ xnb,
                  const unsigned short* __restrict__ inwT,
                  float* __restrict__ xi, float* __restrict__ sz) {
    __shared__ unsigned short Asm[128 * LDK];
    __shared__ unsigned short Bsm[128 * LDK];
    int tid = threadIdx.x;
    int bm = blockIdx.y * 128;
    int bn = blockIdx.x * 128;
    int wave = tid >> 6, lane = tid & 63;
    int wm = (wave & 1) * 64, wn = (wave >> 1) * 64;
    int col15 = lane & 15, quad = lane >> 4;
    floatx4 acc[4][4];
    #pragma unroll
    for (int i = 0; i < 4; i++)
        #pragma unroll
        for (int j = 0; j < 4; j++)
            acc[i][j] = (floatx4){0.f, 0.f, 0.f, 0.f};

    for (int k0 = 0; k0 < DMODEL; k0 += 64) {
        #pragma unroll
        for (int i = 0; i < 4; i++) {
            int c = tid + i * 256;          // 1024 chunks of 8 bf16
            int m = c >> 3, kk = c & 7;
            *(us8*)(&Asm[m * LDK + kk * 8]) =
                *(const us8*)(&xnb[(size_t)(bm + m) * DMODEL + k0 + kk * 8]);
            *(us8*)(&Bsm[m * LDK + kk * 8]) =
                *(const us8*)(&inwT[(size_t)(bn + m) * DMODEL + k0 + kk * 8]);
        }
        __syncthreads();
        #pragma unroll
        for (int k2 = 0; k2 < 2; k2++) {
            bf16x8 af[4], bf_[4];
            #pragma unroll
            for (int mt = 0; mt < 4; mt++)
                af[mt] = *(const bf16x8*)(&Asm[(wm + mt * 16 + col15) * LDK + k2 * 32 + quad * 8]);
            #pragma unroll
            for (int nt = 0; nt < 4; nt++)
                bf_[nt] = *(const bf16x8*)(&Bsm[(wn + nt * 16 + col15) * LDK + k2 * 32 + quad * 8]);
            #pragma unroll
            for (int mt = 0; mt < 4; mt++)
                #pragma unroll
                for (int nt = 0; nt < 4; nt++)
                    acc[mt][nt] = __builtin_amdgcn_mfma_f32_16x16x32_bf16(
                        af[mt], bf_[nt], acc[mt][nt], 0, 0, 0);
        }
        __syncthreads();
    }
    #pragma unroll
    for (int mt = 0; mt < 4; mt++) {
        #pragma unroll
        for (int nt = 0; nt < 4; nt++) {
            #pragma unroll
            for (int r = 0; r < 4; r++) {
                int row = bm + wm + mt * 16 + quad * 4 + r;
                int gn  = bn + wn + nt * 16 + col15;
                float v = acc[mt][nt][r];
                int dir = (gn >= 3072) ? 1 : 0;
                int cc = gn - dir * 3072;
                size_t base = ((size_t)dir * NTOK + row) * DINNER;
                if (cc < DINNER) xi[base + cc] = v;
                else             sz[base + cc - DINNER] = silu_f(v);
            }
        }
    }
}

// ---------------------------------------------------------------------------
// Kernel 4: depthwise causal conv (k=4) + bias + SiLU.
// ---------------------------------------------------------------------------
__global__ void conv_silu(const float* __restrict__ xi,
                          const float* __restrict__ f_cw, const float* __restrict__ f_cb,
                          const float* __restrict__ b_cw, const float* __restrict__ b_cb,
                          float* __restrict__ xc) {
    size_t gid = (size_t)blockIdx.x * 256 + threadIdx.x;
    const size_t total = (size_t)2 * NTOK * DINNER;
    if (gid >= total) return;
    int d = (int)(gid % DINNER);
    size_t r = gid / DINNER;          // (dir*2+b)*LSEQ + t
    int t = (int)(r % LSEQ);
    int b = (int)((r / LSEQ) % NB);
    int dir = (int)(r / (LSEQ * NB));
    const float* cw = dir ? b_cw : f_cw;
    const float* cb = dir ? b_cb : f_cb;
    float acc = cb[d];
    size_t xib = ((size_t)dir * NTOK + (size_t)b * LSEQ) * DINNER;
    #pragma unroll
    for (int k = 0; k < 4; k++) {
        int u = t - 3 + k;
        if (u < 0) continue;
        int l = dir ? (LSEQ - 1 - u) : u;
        acc = fmaf(cw[d * 4 + k], xi[xib + (size_t)l * DINNER + d], acc);
    }
    xc[gid] = silu_f(acc);
}

// ---------------------------------------------------------------------------
// Kernel 5a: bcdt split-K partials. grid (128 row-blocks, KSPLIT).
// part[kc][row][j] = sum over k in [kc*256, kc*256+256).
// ---------------------------------------------------------------------------
__global__ __launch_bounds__(256)
void bcdt_gemm(const float* __restrict__ xc,
               const float* __restrict__ f_xw,
               const float* __restrict__ b_xw,
               float* __restrict__ part) {
    __shared__ float As[64][33];
    __shared__ float Ws[32 * 33];
    int r0 = blockIdx.x * 64;
    int kc = blockIdx.y;
    const float* xw = (r0 >= NTOK) ? b_xw : f_xw;
    int tid = threadIdx.x;
    int m = tid >> 2, jq = tid & 3;
    float acc[9] = {};
    int kend = kc * 256 + 256;
    for (int k0 = kc * 256; k0 < kend; k0 += 32) {
        for (int i = tid; i < 64 * 32; i += 256) {
            int mm = i >> 5, k = i & 31;
            As[mm][k] = xc[((size_t)r0 + mm) * DINNER + k0 + k];
        }
        for (int i = tid; i < 32 * 33; i += 256)
            Ws[i] = xw[(size_t)k0 * 33 + i];
        __syncthreads();
        #pragma unroll 8
        for (int k = 0; k < 32; k++) {
            float a = As[m][k];
            #pragma unroll
            for (int jj = 0; jj < 9; jj++) {
                int j = jq + jj * 4;
                if (j < 33) acc[jj] = fmaf(a, Ws[k * 33 + j], acc[jj]);
            }
        }
        __syncthreads();
    }
    #pragma unroll
    for (int jj = 0; jj < 9; jj++) {
        int j = jq + jj * 4;
        if (j < 33)
            part[((size_t)kc * (2 * NTOK) + r0 + m) * 33 + j] = acc[jj];
    }
}

// ---------------------------------------------------------------------------
// Kernel 5b: reduce split-K partials.
// ---------------------------------------------------------------------------
__global__ void bcdt_reduce(const float* __restrict__ part, float* __restrict__ bcdt) {
    int i = blockIdx.x * 256 + threadIdx.x;
    const int total = 2 * NTOK * NBCDT;       // 270,336
    if (i >= total) return;
    float s = 0.f;
    #pragma unroll
    for (int kc = 0; kc < KSPLIT; kc++)
        s += part[(size_t)kc * total + i];
    bcdt[i] = s;
}

// ---------------------------------------------------------------------------
// Kernel 6a: chunked scan phase 1 -- one THREAD per channel, h[16] in regs.
// grid (6, NCHUNK, 4), block 256 (= 256 channels).
// P_s = exp(A_s * sum(dt))  (== prod exp(dt_t*A_s) exactly in exact arith).
// ---------------------------------------------------------------------------
__global__ __launch_bounds__(256)
void scan_p1(const float* __restrict__ xc, const float* __restrict__ bcdt,
             const float* __restrict__ f_dtw, const float* __restrict__ f_dtb,
             const float* __restrict__ f_Alog,
             const float* __restrict__ b_dtw, const float* __restrict__ b_dtb,
             const float* __restrict__ b_Alog,
             float* __restrict__ Pbuf, float* __restrict__ hloc) {
    int tid = threadIdx.x;
    int d = blockIdx.x * 256 + tid;
    int chunk = blockIdx.y;
    int dirb  = blockIdx.z;
    int dir = dirb >> 1;
    const float* dtw  = dir ? b_dtw  : f_dtw;
    const float* dtb  = dir ? b_dtb  : f_dtb;
    const float* Alog = dir ? b_Alog : f_Alog;
    float dtw_d = dtw[d], dtb_d = dtb[d];
    float A[NSTATE], h[NSTATE];
    #pragma unroll
    for (int s = 0; s < NSTATE; s++) {
        float al = fminf(fmaxf(Alog[d * NSTATE + s], -6.f), 6.f);
        A[s] = -__expf(al);
        h[s] = 0.f;
    }
    float Sdt = 0.f;
    size_t rbase = (size_t)dirb * LSEQ + (size_t)chunk * TC;
    const float* bc = bcdt + rbase * NBCDT;
    const float* xp = xc + rbase * DINNER + d;
    for (int t = 0; t < TC; t++) {
        float xv = xp[(size_t)t * DINNER];
        float dt_raw = bc[t * NBCDT];
        float u = fmaf(dt_raw, dtw_d, dtb_d);
        float dt = fmaxf(u, 0.f) + __logf(1.f + __expf(-fabsf(u)));
        Sdt += dt;
        float dtx = dt * xv;
        #pragma unroll
        for (int s = 0; s < NSTATE; s++) {
            float Bv = bc[t * NBCDT + 1 + s];
            h[s] = clip1e4(fmaf(__expf(dt * A[s]), h[s], dtx * Bv));
        }
    }
    size_t base = ((size_t)chunk * 4 + dirb) * ((size_t)DINNER * NSTATE) + (size_t)d * NSTATE;
    #pragma unroll
    for (int s = 0; s < NSTATE; s++) {
        Pbuf[base + s] = __expf(A[s] * Sdt);
        hloc[base + s] = h[s];
    }
}

// ---------------------------------------------------------------------------
// Kernel 6b: phase 2 -- stitch chunk boundary states.
// ---------------------------------------------------------------------------
__global__ void scan_p2(const float* __restrict__ Pbuf, const float* __restrict__ hloc,
                        float* __restrict__ hin) {
    int i = blockIdx.x * 256 + threadIdx.x;
    float h = 0.f;
    const int stride = 4 * DINNER * NSTATE;   // 98304
    for (int c = 0; c < NCHUNK; c++) {
        size_t idx = (size_t)c * stride + i;
        hin[idx] = h;
        h = clip1e4(fmaf(Pbuf[idx], h, hloc[idx]));
    }
}

// ---------------------------------------------------------------------------
// Kernel 6c: phase 3 -- re-run from stitched h_in, thread-per-channel,
// write bf16 yvb [4096][3072] (fwd cols [0,1536), bwd cols [1536,3072)
// at flipped row) so gemm_out needs no flip logic.
// ---------------------------------------------------------------------------
__global__ __launch_bounds__(256)
void scan_p3(const float* __restrict__ xc, const float* __restrict__ bcdt,
             const float* __restrict__ sz, const float* __restrict__ hin,
             const float* __restrict__ f_dtw, const float* __restrict__ f_dtb,
             const float* __restrict__ f_Alog, const float* __restrict__ f_D,
             const float* __restrict__ b_dtw, const float* __restrict__ b_dtb,
             const float* __restrict__ b_Alog, const float* __restrict__ b_D,
             unsigned short* __restrict__ yvb) {
    int tid = threadIdx.x;
    int d = blockIdx.x * 256 + tid;
    int chunk = blockIdx.y;
    int dirb  = blockIdx.z;
    int dir = dirb >> 1, b = dirb & 1;
    const float* dtw  = dir ? b_dtw  : f_dtw;
    const float* dtb  = dir ? b_dtb  : f_dtb;
    const float* Alog = dir ? b_Alog : f_Alog;
    const float* Dp   = dir ? b_D    : f_D;
    float dtw_d = dtw[d], dtb_d = dtb[d], D_d = Dp[d];
    float A[NSTATE], h[NSTATE];
    size_t hbase = ((size_t)chunk * 4 + dirb) * ((size_t)DINNER * NSTATE) + (size_t)d * NSTATE;
    #pragma unroll
    for (int s = 0; s < NSTATE; s++) {
        float al = fminf(fmaxf(Alog[d * NSTATE + s], -6.f), 6.f);
        A[s] = -__expf(al);
        h[s] = hin[hbase + s];
    }
    size_t rbase = (size_t)dirb * LSEQ + (size_t)chunk * TC;
    const float* bc = bcdt + rbase * NBCDT;
    const float* xp = xc + rbase * DINNER + d;
    int t0 = chunk * TC;
    for (int t = 0; t < TC; t++) {
        float xv = xp[(size_t)t * DINNER];
        float dt_raw = bc[t * NBCDT];
        float u = fmaf(dt_raw, dtw_d, dtb_d);
        float dt = fmaxf(u, 0.f) + __logf(1.f + __expf(-fabsf(u)));
        float dtx = dt * xv;
        float p = 0.f;
        #pragma unroll
        for (int s = 0; s < NSTATE; s++) {
            float Bv = bc[t * NBCDT + 1 + s];
            float Cv = bc[t * NBCDT + 1 + NSTATE + s];
            h[s] = clip1e4(fmaf(__expf(dt * A[s]), h[s], dtx * Bv));
            p = fmaf(h[s], Cv, p);
        }
        int tt = t0 + t;
        int l = dir ? (LSEQ - 1 - tt) : tt;
        float szv = sz[((size_t)dir * NTOK + (size_t)b * LSEQ + l) * DINNER + d];
        float y = (p + xv * D_d) * szv;
        int row = b * LSEQ + l;
        yvb[(size_t)row * 3072 + dir * DINNER + d] = f2bf(y);
    }
}

// ---------------------------------------------------------------------------
// Kernel 7: output GEMM via MFMA bf16 + residual.
// ---------------------------------------------------------------------------
__global__ __launch_bounds__(256)
void gemm_out_mfma(const unsigned short* __restrict__ yvb,
                   const unsigned short* __restrict__ outwT,
                   const float* __restrict__ x,
                   float* __restrict__ out) {
    __shared__ unsigned short Asm[128 * LDK];
    __shared__ unsigned short Bsm[64 * LDK];
    int tid = threadIdx.x;
    int bm = blockIdx.y * 128;
    int bn = blockIdx.x * 64;
    int wave = tid >> 6, lane = tid & 63;
    int wm = (wave & 1) * 64, wn = (wave >> 1) * 32;
    int col15 = lane & 15, quad = lane >> 4;
    floatx4 acc[4][2];
    #pragma unroll
    for (int i = 0; i < 4; i++)
        #pragma unroll
        for (int j = 0; j < 2; j++)
            acc[i][j] = (floatx4){0.f, 0.f, 0.f, 0.f};

    for (int k0 = 0; k0 < 2 * DINNER; k0 += 64) {
        #pragma unroll
        for (int i = 0; i < 4; i++) {
            int c = tid + i * 256;
            int m = c >> 3, kk = c & 7;
            *(us8*)(&Asm[m * LDK + kk * 8]) =
                *(const us8*)(&yvb[(size_t)(bm + m) * 3072 + k0 + kk * 8]);
        }
        #pragma unroll
        for (int i = 0; i < 2; i++) {
            int c = tid + i * 256;
            int n = c >> 3, kk = c & 7;
            *(us8*)(&Bsm[n * LDK + kk * 8]) =
                *(const us8*)(&outwT[(size_t)(bn + n) * 3072 + k0 + kk * 8]);
        }
        __syncthreads();
        #pragma unroll
        for (int k2 = 0; k2 < 2; k2++) {
            bf16x8 af[4], bf_[2];
            #pragma unroll
            for (int mt = 0; mt < 4; mt++)
                af[mt] = *(const bf16x8*)(&Asm[(wm + mt * 16 + col15) * LDK + k2 * 32 + quad * 8]);
            #pragma unroll
            for (int nt = 0; nt < 2; nt++)
                bf_[nt] = *(const bf16x8*)(&Bsm[(wn + nt * 16 + col15) * LDK + k2 * 32 + quad * 8]);
            #pragma unroll
            for (int mt = 0; mt < 4; mt++)
                #pragma unroll
                for (int nt = 0; nt < 2; nt++)
                    acc[mt][nt] = __builtin_amdgcn_mfma_f32_16x16x32_bf16(
                        af[mt], bf_[nt], acc[mt][nt], 0, 0, 0);
        }
        __syncthreads();
    }
    #pragma unroll
    for (int mt = 0; mt < 4; mt++) {
        #pragma unroll
        for (int nt = 0; nt < 2; nt++) {
            #pragma unroll
            for (int r = 0; r < 4; r++) {
                int row = bm + wm + mt * 16 + quad * 4 + r;
                int gn  = bn + wn + nt * 16 + col15;
                out[(size_t)row * DMODEL + gn] = acc[mt][nt][r] + x[(size_t)row * DMODEL + gn];
            }
        }
    }
}

// ---------------------------------------------------------------------------
extern "C" void kernel_launch(void* const* d_in, const int* in_sizes, int n_in,
                              void* d_out, int out_size, void* d_ws, size_t ws_size,
                              hipStream_t stream) {
    const float* x     = (const float*)d_in[0];
    const float* ln_g  = (const float*)d_in[1];
    const float* ln_b  = (const float*)d_in[2];
    const float* alpha = (const float*)d_in[3];
    const float* f_inw  = (const float*)d_in[4];
    const float* f_cw   = (const float*)d_in[5];
    const float* f_cb   = (const float*)d_in[6];
    const float* f_xw   = (const float*)d_in[7];
    const float* f_dtw  = (const float*)d_in[8];
    const float* f_dtb  = (const float*)d_in[9];
    const float* f_Alog = (const float*)d_in[10];
    const float* f_D    = (const float*)d_in[11];
    const float* f_outw = (const float*)d_in[12];
    const float* b_inw  = (const float*)d_in[13];
    const float* b_cw   = (const float*)d_in[14];
    const float* b_cb   = (const float*)d_in[15];
    const float* b_xw   = (const float*)d_in[16];
    const float* b_dtw  = (const float*)d_in[17];
    const float* b_dtb  = (const float*)d_in[18];
    const float* b_Alog = (const float*)d_in[19];
    const float* b_D    = (const float*)d_in[20];
    const float* b_outw = (const float*)d_in[21];
    float* out = (float*)d_out;

    // Workspace layout (float offsets; identical footprint to round 3: ~179MB):
    float* ws = (float*)d_ws;
    const size_t big = (size_t)2 * NTOK * DINNER;       // 12,582,912
    float* r_xnb  = ws;                                  // 1,572,864 fl (xnb bf16) -> Pbuf
    float* r_inwT = r_xnb + 1572864;                     // 2,359,296 fl (inwT bf16) -> bcdt_part -> hloc
    float* r_outwT= r_inwT + 2359296;                    // 1,179,648 fl (outwT bf16)
    float* xi     = r_outwT + 1179648;                   // big (fp32) -> yvb (bf16)
    float* sz     = xi + big;                            // big
    float* xc     = sz + big;                            // big
    float* bcdt   = xc + big;                            // 270,336
    float* hin    = bcdt + (size_t)2 * NTOK * NBCDT;     // 1,572,864

    unsigned short* xnb   = (unsigned short*)r_xnb;
    unsigned short* inwT  = (unsigned short*)r_inwT;
    unsigned short* outwT = (unsigned short*)r_outwT;
    unsigned short* yvb   = (unsigned short*)xi;         // alias: xi dead after conv
    float* Pbuf = r_xnb;                                  // alias: xnb dead after gemm_xz
    float* bcdt_part = r_inwT;                            // alias: inwT dead after gemm_xz (needs 1,622,016 <= 2,359,296)
    float* hloc = r_inwT;                                 // alias: bcdt_part dead after bcdt_reduce

    // 1. LayerNorm -> bf16
    ln_kernel<<<NTOK, 256, 0, stream>>>(x, ln_g, ln_b, xnb);
    // 2. weight transpose-casts
    {
        dim3 g1(6144 / 32, DMODEL / 32);
        cast_inwT<<<g1, 256, 0, stream>>>(f_inw, b_inw, inwT);
        dim3 g2(DMODEL / 32, 3072 / 32);
        cast_outwT<<<g2, 256, 0, stream>>>(f_outw, b_outw, alpha, outwT);
    }
    // 3. xz GEMM (MFMA)
    {
        dim3 grid(6144 / 128, NTOK / 128);
        gemm_xz_mfma<<<grid, 256, 0, stream>>>(xnb, inwT, xi, sz);
    }
    // 4. conv + silu
    {
        size_t total = (size_t)2 * NTOK * DINNER;
        conv_silu<<<(total + 255) / 256, 256, 0, stream>>>(xi, f_cw, f_cb, b_cw, b_cb, xc);
    }
    // 5. bcdt split-K GEMM + reduce
    {
        dim3 g(2 * NTOK / 64, KSPLIT);
        bcdt_gemm<<<g, 256, 0, stream>>>(xc, f_xw, b_xw, bcdt_part);
        bcdt_reduce<<<(2 * NTOK * NBCDT + 255) / 256, 256, 0, stream>>>(bcdt_part, bcdt);
    }
    // 6. chunked scan (thread-per-channel)
    {
        dim3 grid1(DINNER / 256, NCHUNK, 4);
        scan_p1<<<grid1, 256, 0, stream>>>(xc, bcdt,
                                           f_dtw, f_dtb, f_Alog,
                                           b_dtw, b_dtb, b_Alog, Pbuf, hloc);
        scan_p2<<<(4 * DINNER * NSTATE) / 256, 256, 0, stream>>>(Pbuf, hloc, hin);
        scan_p3<<<grid1, 256, 0, stream>>>(xc, bcdt, sz, hin,
                                           f_dtw, f_dtb, f_Alog, f_D,
                                           b_dtw, b_dtb, b_Alog, b_D, yvb);
    }
    // 7. out GEMM (MFMA) + residual
    {
        dim3 grid(DMODEL / 64, NTOK / 128);
        gemm_out_mfma<<<grid, 256, 0, stream>>>(yvb, outwT, x, out);
    }
}

// Round 5
// 496.467 us; speedup vs baseline: 6.7928x; 1.1232x over previous
//
#include <hip/hip_runtime.h>
#include <cstddef>
#include <cstdint>

// Problem constants (fixed by reference)
#define DMODEL 768
#define DINNER 1536
#define NSTATE 16
#define LSEQ   2048
#define NB     2
#define NTOK   (NB*LSEQ)        // 4096 tokens
#define NBCDT  33               // 1 + 2*16

// Chunked scan parameters
#define TC     64               // timesteps per chunk (was 128; halved for occupancy)
#define NCHUNK (LSEQ/TC)        // 32
#define KSPLIT 6                // bcdt split-K factor (1536/256)

// MFMA GEMM params
#define LDK 72                  // padded LDS stride in bf16 elems (64 + 8)

typedef __bf16 bf16x8 __attribute__((ext_vector_type(8)));
typedef float  floatx4 __attribute__((ext_vector_type(4)));
typedef unsigned short us8 __attribute__((ext_vector_type(8)));

__device__ __forceinline__ float silu_f(float x) { return x / (1.f + expf(-x)); }
__device__ __forceinline__ float clip1e4(float x) { return fminf(fmaxf(x, -1e4f), 1e4f); }
__device__ __forceinline__ unsigned short f2bf(float f) {   // RNE float->bf16 bits
    unsigned int u = __float_as_uint(f);
    unsigned int r = u + 0x7fffu + ((u >> 16) & 1u);
    return (unsigned short)(r >> 16);
}

// ---------------------------------------------------------------------------
// Kernel 1: LayerNorm -> bf16 output. one block per token row.
// ---------------------------------------------------------------------------
__global__ void ln_kernel(const float* __restrict__ x,
                          const float* __restrict__ g,
                          const float* __restrict__ be,
                          unsigned short* __restrict__ xnb) {
    int row = blockIdx.x;
    int tid = threadIdx.x;
    const float* xr = x + (size_t)row * DMODEL;
    float s = 0.f, ss = 0.f;
    for (int i = tid; i < DMODEL; i += 256) {
        float v = xr[i];
        s += v; ss += v * v;
    }
    for (int o = 32; o >= 1; o >>= 1) {
        s  += __shfl_xor(s,  o, 64);
        ss += __shfl_xor(ss, o, 64);
    }
    __shared__ float sS[4], sSS[4];
    int w = tid >> 6;
    if ((tid & 63) == 0) { sS[w] = s; sSS[w] = ss; }
    __syncthreads();
    s  = sS[0] + sS[1] + sS[2] + sS[3];
    ss = sSS[0] + sSS[1] + sSS[2] + sSS[3];
    float mu = s / DMODEL;
    float var = ss / DMODEL - mu * mu;
    float rstd = rsqrtf(var + 1e-5f);
    unsigned short* xo = xnb + (size_t)row * DMODEL;
    for (int i = tid; i < DMODEL; i += 256)
        xo[i] = f2bf((xr[i] - mu) * rstd * g[i] + be[i]);
}

// ---------------------------------------------------------------------------
// Kernel 2a: transpose-cast in-proj weights: inwT[n][k] (bf16), n in [0,6144)
// ---------------------------------------------------------------------------
__global__ __launch_bounds__(256)
void cast_inwT(const float* __restrict__ fw, const float* __restrict__ bw,
               unsigned short* __restrict__ wT) {
    __shared__ float t[32][33];
    int n0 = blockIdx.x * 32;     // 192 blocks
    int k0 = blockIdx.y * 32;     // 24 blocks
    int tid = threadIdx.x;
    int lr = tid >> 5, lc = tid & 31;
    const float* w = (n0 >= 3072) ? bw : fw;
    int nb = (n0 >= 3072) ? (n0 - 3072) : n0;
    #pragma unroll
    for (int r = 0; r < 4; r++)
        t[r * 8 + lr][lc] = w[(size_t)(k0 + r * 8 + lr) * 3072 + nb + lc];
    __syncthreads();
    #pragma unroll
    for (int r = 0; r < 4; r++)
        wT[(size_t)(n0 + r * 8 + lr) * DMODEL + k0 + lc] = f2bf(t[lc][r * 8 + lr]);
}

// ---------------------------------------------------------------------------
// Kernel 2b: transpose-cast out-proj weights with blend scale folded in.
// ---------------------------------------------------------------------------
__global__ __launch_bounds__(256)
void cast_outwT(const float* __restrict__ fw, const float* __restrict__ bw,
                const float* __restrict__ alpha, unsigned short* __restrict__ wT) {
    __shared__ float t[32][33];
    float a = 1.f / (1.f + expf(-alpha[0]));
    int n0 = blockIdx.x * 32;     // 24 blocks
    int k0 = blockIdx.y * 32;     // 96 blocks
    int tid = threadIdx.x;
    int lr = tid >> 5, lc = tid & 31;
    const float* w = (k0 >= DINNER) ? bw : fw;
    float sc = (k0 >= DINNER) ? (1.f - a) : a;
    int kb = (k0 >= DINNER) ? (k0 - DINNER) : k0;
    #pragma unroll
    for (int r = 0; r < 4; r++)
        t[r * 8 + lr][lc] = w[(size_t)(kb + r * 8 + lr) * DMODEL + n0 + lc];
    __syncthreads();
    #pragma unroll
    for (int r = 0; r < 4; r++)
        wT[(size_t)(n0 + r * 8 + lr) * 3072 + k0 + lc] = f2bf(sc * t[lc][r * 8 + lr]);
}

// ---------------------------------------------------------------------------
// Kernel 3: xz GEMM via MFMA bf16.  M=4096, N=6144, K=768.
// ---------------------------------------------------------------------------
__global__ __launch_bounds__(256)
void gemm_xz_mfma(const unsigned short* __restrict__ xnb,
                  const unsigned short* __restrict__ inwT,
                  float* __restrict__ xi, float* __restrict__ sz) {
    __shared__ unsigned short Asm[128 * LDK];
    __shared__ unsigned short Bsm[128 * LDK];
    int tid = threadIdx.x;
    int bm = blockIdx.y * 128;
    int bn = blockIdx.x * 128;
    int wave = tid >> 6, lane = tid & 63;
    int wm = (wave & 1) * 64, wn = (wave >> 1) * 64;
    int col15 = lane & 15, quad = lane >> 4;
    floatx4 acc[4][4];
    #pragma unroll
    for (int i = 0; i < 4; i++)
        #pragma unroll
        for (int j = 0; j < 4; j++)
            acc[i][j] = (floatx4){0.f, 0.f, 0.f, 0.f};

    for (int k0 = 0; k0 < DMODEL; k0 += 64) {
        #pragma unroll
        for (int i = 0; i < 4; i++) {
            int c = tid + i * 256;          // 1024 chunks of 8 bf16
            int m = c >> 3, kk = c & 7;
            *(us8*)(&Asm[m * LDK + kk * 8]) =
                *(const us8*)(&xnb[(size_t)(bm + m) * DMODEL + k0 + kk * 8]);
            *(us8*)(&Bsm[m * LDK + kk * 8]) =
                *(const us8*)(&inwT[(size_t)(bn + m) * DMODEL + k0 + kk * 8]);
        }
        __syncthreads();
        #pragma unroll
        for (int k2 = 0; k2 < 2; k2++) {
            bf16x8 af[4], bf_[4];
            #pragma unroll
            for (int mt = 0; mt < 4; mt++)
                af[mt] = *(const bf16x8*)(&Asm[(wm + mt * 16 + col15) * LDK + k2 * 32 + quad * 8]);
            #pragma unroll
            for (int nt = 0; nt < 4; nt++)
                bf_[nt] = *(const bf16x8*)(&Bsm[(wn + nt * 16 + col15) * LDK + k2 * 32 + quad * 8]);
            #pragma unroll
            for (int mt = 0; mt < 4; mt++)
                #pragma unroll
                for (int nt = 0; nt < 4; nt++)
                    acc[mt][nt] = __builtin_amdgcn_mfma_f32_16x16x32_bf16(
                        af[mt], bf_[nt], acc[mt][nt], 0, 0, 0);
        }
        __syncthreads();
    }
    #pragma unroll
    for (int mt = 0; mt < 4; mt++) {
        #pragma unroll
        for (int nt = 0; nt < 4; nt++) {
            #pragma unroll
            for (int r = 0; r < 4; r++) {
                int row = bm + wm + mt * 16 + quad * 4 + r;
                int gn  = bn + wn + nt * 16 + col15;
                float v = acc[mt][nt][r];
                int dir = (gn >= 3072) ? 1 : 0;
                int cc = gn - dir * 3072;
                size_t base = ((size_t)dir * NTOK + row) * DINNER;
                if (cc < DINNER) xi[base + cc] = v;
                else             sz[base + cc - DINNER] = silu_f(v);
            }
        }
    }
}

// ---------------------------------------------------------------------------
// Kernel 4: depthwise causal conv (k=4) + bias + SiLU.  float4-vectorized:
// one thread = 4 consecutive channels at one (dirb, t).
// ---------------------------------------------------------------------------
__global__ void conv_silu(const float* __restrict__ xi,
                          const float* __restrict__ f_cw, const float* __restrict__ f_cb,
                          const float* __restrict__ b_cw, const float* __restrict__ b_cb,
                          float* __restrict__ xc) {
    const int D4 = DINNER / 4;        // 384
    size_t gid = (size_t)blockIdx.x * 256 + threadIdx.x;
    const size_t total = (size_t)2 * NTOK * D4;
    if (gid >= total) return;
    int d4 = (int)(gid % D4);
    size_t r = gid / D4;              // (dir*2+b)*LSEQ + t
    int t = (int)(r % LSEQ);
    int b = (int)((r / LSEQ) % NB);
    int dir = (int)(r / (LSEQ * NB));
    int d = d4 * 4;
    const float* cw = dir ? b_cw : f_cw;
    const float* cb = dir ? b_cb : f_cb;
    float4 w0 = *(const float4*)(cw + (size_t)(d + 0) * 4);
    float4 w1 = *(const float4*)(cw + (size_t)(d + 1) * 4);
    float4 w2 = *(const float4*)(cw + (size_t)(d + 2) * 4);
    float4 w3 = *(const float4*)(cw + (size_t)(d + 3) * 4);
    float4 acc = *(const float4*)(cb + d);
    size_t xib = ((size_t)dir * NTOK + (size_t)b * LSEQ) * DINNER + d;
    // k index into weights; tap at original position u = t-3+k
    {
        const float wk[4][4] = {{w0.x, w1.x, w2.x, w3.x},
                                {w0.y, w1.y, w2.y, w3.y},
                                {w0.z, w1.z, w2.z, w3.z},
                                {w0.w, w1.w, w2.w, w3.w}};
        #pragma unroll
        for (int k = 0; k < 4; k++) {
            int u = t - 3 + k;
            if (u < 0) continue;
            int l = dir ? (LSEQ - 1 - u) : u;
            float4 xv = *(const float4*)(xi + xib + (size_t)l * DINNER);
            acc.x = fmaf(wk[k][0], xv.x, acc.x);
            acc.y = fmaf(wk[k][1], xv.y, acc.y);
            acc.z = fmaf(wk[k][2], xv.z, acc.z);
            acc.w = fmaf(wk[k][3], xv.w, acc.w);
        }
    }
    float4 o;
    o.x = silu_f(acc.x); o.y = silu_f(acc.y);
    o.z = silu_f(acc.z); o.w = silu_f(acc.w);
    *(float4*)(xc + r * DINNER + d) = o;
}

// ---------------------------------------------------------------------------
// Kernel 5a: bcdt split-K partials. grid (128 row-blocks, KSPLIT).
// ---------------------------------------------------------------------------
__global__ __launch_bounds__(256)
void bcdt_gemm(const float* __restrict__ xc,
               const float* __restrict__ f_xw,
               const float* __restrict__ b_xw,
               float* __restrict__ part) {
    __shared__ float As[64][33];
    __shared__ float Ws[32 * 33];
    int r0 = blockIdx.x * 64;
    int kc = blockIdx.y;
    const float* xw = (r0 >= NTOK) ? b_xw : f_xw;
    int tid = threadIdx.x;
    int m = tid >> 2, jq = tid & 3;
    float acc[9] = {};
    int kend = kc * 256 + 256;
    for (int k0 = kc * 256; k0 < kend; k0 += 32) {
        for (int i = tid; i < 64 * 32; i += 256) {
            int mm = i >> 5, k = i & 31;
            As[mm][k] = xc[((size_t)r0 + mm) * DINNER + k0 + k];
        }
        for (int i = tid; i < 32 * 33; i += 256)
            Ws[i] = xw[(size_t)k0 * 33 + i];
        __syncthreads();
        #pragma unroll 8
        for (int k = 0; k < 32; k++) {
            float a = As[m][k];
            #pragma unroll
            for (int jj = 0; jj < 9; jj++) {
                int j = jq + jj * 4;
                if (j < 33) acc[jj] = fmaf(a, Ws[k * 33 + j], acc[jj]);
            }
        }
        __syncthreads();
    }
    #pragma unroll
    for (int jj = 0; jj < 9; jj++) {
        int j = jq + jj * 4;
        if (j < 33)
            part[((size_t)kc * (2 * NTOK) + r0 + m) * 33 + j] = acc[jj];
    }
}

// ---------------------------------------------------------------------------
// Kernel 5b: reduce split-K partials.
// ---------------------------------------------------------------------------
__global__ void bcdt_reduce(const float* __restrict__ part, float* __restrict__ bcdt) {
    int i = blockIdx.x * 256 + threadIdx.x;
    const int total = 2 * NTOK * NBCDT;       // 270,336
    if (i >= total) return;
    float s = 0.f;
    #pragma unroll
    for (int kc = 0; kc < KSPLIT; kc++)
        s += part[(size_t)kc * total + i];
    bcdt[i] = s;
}

// ---------------------------------------------------------------------------
// Kernel 6a: chunked scan phase 1 -- one THREAD per channel, h[16] in regs.
// grid (6, NCHUNK, 4), block 256 (= 256 channels).
// ---------------------------------------------------------------------------
__global__ __launch_bounds__(256)
void scan_p1(const float* __restrict__ xc, const float* __restrict__ bcdt,
             const float* __restrict__ f_dtw, const float* __restrict__ f_dtb,
             const float* __restrict__ f_Alog,
             const float* __restrict__ b_dtw, const float* __restrict__ b_dtb,
             const float* __restrict__ b_Alog,
             float* __restrict__ Pbuf, float* __restrict__ hloc) {
    int tid = threadIdx.x;
    int d = blockIdx.x * 256 + tid;
    int chunk = blockIdx.y;
    int dirb  = blockIdx.z;
    int dir = dirb >> 1;
    const float* dtw  = dir ? b_dtw  : f_dtw;
    const float* dtb  = dir ? b_dtb  : f_dtb;
    const float* Alog = dir ? b_Alog : f_Alog;
    float dtw_d = dtw[d], dtb_d = dtb[d];
    float A[NSTATE], h[NSTATE];
    #pragma unroll
    for (int s = 0; s < NSTATE; s++) {
        float al = fminf(fmaxf(Alog[d * NSTATE + s], -6.f), 6.f);
        A[s] = -__expf(al);
        h[s] = 0.f;
    }
    float Sdt = 0.f;
    size_t rbase = (size_t)dirb * LSEQ + (size_t)chunk * TC;
    const float* bc = bcdt + rbase * NBCDT;
    const float* xp = xc + rbase * DINNER + d;
    for (int t = 0; t < TC; t++) {
        float xv = xp[(size_t)t * DINNER];
        float dt_raw = bc[t * NBCDT];
        float u = fmaf(dt_raw, dtw_d, dtb_d);
        float dt = fmaxf(u, 0.f) + __logf(1.f + __expf(-fabsf(u)));
        Sdt += dt;
        float dtx = dt * xv;
        #pragma unroll
        for (int s = 0; s < NSTATE; s++) {
            float Bv = bc[t * NBCDT + 1 + s];
            h[s] = clip1e4(fmaf(__expf(dt * A[s]), h[s], dtx * Bv));
        }
    }
    size_t base = ((size_t)chunk * 4 + dirb) * ((size_t)DINNER * NSTATE) + (size_t)d * NSTATE;
    #pragma unroll
    for (int s = 0; s < NSTATE; s++) {
        Pbuf[base + s] = __expf(A[s] * Sdt);
        hloc[base + s] = h[s];
    }
}

// ---------------------------------------------------------------------------
// Kernel 6b: phase 2 -- stitch chunk boundary states.
// ---------------------------------------------------------------------------
__global__ void scan_p2(const float* __restrict__ Pbuf, const float* __restrict__ hloc,
                        float* __restrict__ hin) {
    int i = blockIdx.x * 256 + threadIdx.x;
    float h = 0.f;
    const int stride = 4 * DINNER * NSTATE;   // 98304
    for (int c = 0; c < NCHUNK; c++) {
        size_t idx = (size_t)c * stride + i;
        hin[idx] = h;
        h = clip1e4(fmaf(Pbuf[idx], h, hloc[idx]));
    }
}

// ---------------------------------------------------------------------------
// Kernel 6c: phase 3 -- re-run from stitched h_in, thread-per-channel,
// write bf16 yvb [4096][3072].
// ---------------------------------------------------------------------------
__global__ __launch_bounds__(256)
void scan_p3(const float* __restrict__ xc, const float* __restrict__ bcdt,
             const float* __restrict__ sz, const float* __restrict__ hin,
             const float* __restrict__ f_dtw, const float* __restrict__ f_dtb,
             const float* __restrict__ f_Alog, const float* __restrict__ f_D,
             const float* __restrict__ b_dtw, const float* __restrict__ b_dtb,
             const float* __restrict__ b_Alog, const float* __restrict__ b_D,
             unsigned short* __restrict__ yvb) {
    int tid = threadIdx.x;
    int d = blockIdx.x * 256 + tid;
    int chunk = blockIdx.y;
    int dirb  = blockIdx.z;
    int dir = dirb >> 1, b = dirb & 1;
    const float* dtw  = dir ? b_dtw  : f_dtw;
    const float* dtb  = dir ? b_dtb  : f_dtb;
    const float* Alog = dir ? b_Alog : f_Alog;
    const float* Dp   = dir ? b_D    : f_D;
    float dtw_d = dtw[d], dtb_d = dtb[d], D_d = Dp[d];
    float A[NSTATE], h[NSTATE];
    size_t hbase = ((size_t)chunk * 4 + dirb) * ((size_t)DINNER * NSTATE) + (size_t)d * NSTATE;
    #pragma unroll
    for (int s = 0; s < NSTATE; s++) {
        float al = fminf(fmaxf(Alog[d * NSTATE + s], -6.f), 6.f);
        A[s] = -__expf(al);
        h[s] = hin[hbase + s];
    }
    size_t rbase = (size_t)dirb * LSEQ + (size_t)chunk * TC;
    const float* bc = bcdt + rbase * NBCDT;
    const float* xp = xc + rbase * DINNER + d;
    int t0 = chunk * TC;
    for (int t = 0; t < TC; t++) {
        float xv = xp[(size_t)t * DINNER];
        float dt_raw = bc[t * NBCDT];
        float u = fmaf(dt_raw, dtw_d, dtb_d);
        float dt = fmaxf(u, 0.f) + __logf(1.f + __expf(-fabsf(u)));
        float dtx = dt * xv;
        float p = 0.f;
        #pragma unroll
        for (int s = 0; s < NSTATE; s++) {
            float Bv = bc[t * NBCDT + 1 + s];
            float Cv = bc[t * NBCDT + 1 + NSTATE + s];
            h[s] = clip1e4(fmaf(__expf(dt * A[s]), h[s], dtx * Bv));
            p = fmaf(h[s], Cv, p);
        }
        int tt = t0 + t;
        int l = dir ? (LSEQ - 1 - tt) : tt;
        float szv = sz[((size_t)dir * NTOK + (size_t)b * LSEQ + l) * DINNER + d];
        float y = (p + xv * D_d) * szv;
        int row = b * LSEQ + l;
        yvb[(size_t)row * 3072 + dir * DINNER + d] = f2bf(y);
    }
}

// ---------------------------------------------------------------------------
// Kernel 7: output GEMM via MFMA bf16 + residual.
// ---------------------------------------------------------------------------
__global__ __launch_bounds__(256)
void gemm_out_mfma(const unsigned short* __restrict__ yvb,
                   const unsigned short* __restrict__ outwT,
                   const float* __restrict__ x,
                   float* __restrict__ out) {
    __shared__ unsigned short Asm[128 * LDK];
    __shared__ unsigned short Bsm[64 * LDK];
    int tid = threadIdx.x;
    int bm = blockIdx.y * 128;
    int bn = blockIdx.x * 64;
    int wave = tid >> 6, lane = tid & 63;
    int wm = (wave & 1) * 64, wn = (wave >> 1) * 32;
    int col15 = lane & 15, quad = lane >> 4;
    floatx4 acc[4][2];
    #pragma unroll
    for (int i = 0; i < 4; i++)
        #pragma unroll
        for (int j = 0; j < 2; j++)
            acc[i][j] = (floatx4){0.f, 0.f, 0.f, 0.f};

    for (int k0 = 0; k0 < 2 * DINNER; k0 += 64) {
        #pragma unroll
        for (int i = 0; i < 4; i++) {
            int c = tid + i * 256;
            int m = c >> 3, kk = c & 7;
            *(us8*)(&Asm[m * LDK + kk * 8]) =
                *(const us8*)(&yvb[(size_t)(bm + m) * 3072 + k0 + kk * 8]);
        }
        #pragma unroll
        for (int i = 0; i < 2; i++) {
            int c = tid + i * 256;
            int n = c >> 3, kk = c & 7;
            *(us8*)(&Bsm[n * LDK + kk * 8]) =
                *(const us8*)(&outwT[(size_t)(bn + n) * 3072 + k0 + kk * 8]);
        }
        __syncthreads();
        #pragma unroll
        for (int k2 = 0; k2 < 2; k2++) {
            bf16x8 af[4], bf_[2];
            #pragma unroll
            for (int mt = 0; mt < 4; mt++)
                af[mt] = *(const bf16x8*)(&Asm[(wm + mt * 16 + col15) * LDK + k2 * 32 + quad * 8]);
            #pragma unroll
            for (int nt = 0; nt < 2; nt++)
                bf_[nt] = *(const bf16x8*)(&Bsm[(wn + nt * 16 + col15) * LDK + k2 * 32 + quad * 8]);
            #pragma unroll
            for (int mt = 0; mt < 4; mt++)
                #pragma unroll
                for (int nt = 0; nt < 2; nt++)
                    acc[mt][nt] = __builtin_amdgcn_mfma_f32_16x16x32_bf16(
                        af[mt], bf_[nt], acc[mt][nt], 0, 0, 0);
        }
        __syncthreads();
    }
    #pragma unroll
    for (int mt = 0; mt < 4; mt++) {
        #pragma unroll
        for (int nt = 0; nt < 2; nt++) {
            #pragma unroll
            for (int r = 0; r < 4; r++) {
                int row = bm + wm + mt * 16 + quad * 4 + r;
                int gn  = bn + wn + nt * 16 + col15;
                out[(size_t)row * DMODEL + gn] = acc[mt][nt][r] + x[(size_t)row * DMODEL + gn];
            }
        }
    }
}

// ---------------------------------------------------------------------------
extern "C" void kernel_launch(void* const* d_in, const int* in_sizes, int n_in,
                              void* d_out, int out_size, void* d_ws, size_t ws_size,
                              hipStream_t stream) {
    const float* x     = (const float*)d_in[0];
    const float* ln_g  = (const float*)d_in[1];
    const float* ln_b  = (const float*)d_in[2];
    const float* alpha = (const float*)d_in[3];
    const float* f_inw  = (const float*)d_in[4];
    const float* f_cw   = (const float*)d_in[5];
    const float* f_cb   = (const float*)d_in[6];
    const float* f_xw   = (const float*)d_in[7];
    const float* f_dtw  = (const float*)d_in[8];
    const float* f_dtb  = (const float*)d_in[9];
    const float* f_Alog = (const float*)d_in[10];
    const float* f_D    = (const float*)d_in[11];
    const float* f_outw = (const float*)d_in[12];
    const float* b_inw  = (const float*)d_in[13];
    const float* b_cw   = (const float*)d_in[14];
    const float* b_cb   = (const float*)d_in[15];
    const float* b_xw   = (const float*)d_in[16];
    const float* b_dtw  = (const float*)d_in[17];
    const float* b_dtb  = (const float*)d_in[18];
    const float* b_Alog = (const float*)d_in[19];
    const float* b_D    = (const float*)d_in[20];
    const float* b_outw = (const float*)d_in[21];
    float* out = (float*)d_out;

    // Workspace layout (float offsets; same total footprint as round 4: ~179MB)
    float* ws = (float*)d_ws;
    const size_t big = (size_t)2 * NTOK * DINNER;       // 12,582,912
    const size_t SUM = (size_t)NCHUNK * 4 * DINNER * NSTATE;  // 3,145,728 (TC=64)
    float* r_xnb  = ws;                                  // 1,572,864 fl (xnb bf16); dead after gemm_xz
    float* r_inwT = r_xnb + 1572864;                     // 2,359,296 fl (inwT bf16); dead after gemm_xz
    float* r_outwT= r_inwT + 2359296;                    // 1,179,648 fl (outwT bf16); live till gemm_out
    float* xi     = r_outwT + 1179648;                   // big; dead after conv
    float* sz     = xi + big;                            // big
    float* xc     = sz + big;                            // big
    float* bcdt   = xc + big;                            // 270,336

    unsigned short* xnb   = (unsigned short*)r_xnb;
    unsigned short* inwT  = (unsigned short*)r_inwT;
    unsigned short* outwT = (unsigned short*)r_outwT;
    // Aliases (lifetime-checked):
    unsigned short* yvb = (unsigned short*)xi;           // xi[0 : 6.29M fl] as 12.58M shorts
    float* Pbuf = xi + 6291456;                          // xi[6.29M : 9.44M] (SUM)
    float* hloc = xi + 9437184;                          // xi[9.44M : 12.58M] (SUM)
    float* bcdt_part = r_inwT;                           // 1,622,016 fl <= 2,359,296; dead after reduce
    float* hin  = r_xnb;                                 // SUM = 3,145,728 fl, spans r_xnb + first part
                                                         // of r_inwT (both dead; bcdt_part dead before
                                                         // scan_p2 writes hin)

    // 1. LayerNorm -> bf16
    ln_kernel<<<NTOK, 256, 0, stream>>>(x, ln_g, ln_b, xnb);
    // 2. weight transpose-casts
    {
        dim3 g1(6144 / 32, DMODEL / 32);
        cast_inwT<<<g1, 256, 0, stream>>>(f_inw, b_inw, inwT);
        dim3 g2(DMODEL / 32, 3072 / 32);
        cast_outwT<<<g2, 256, 0, stream>>>(f_outw, b_outw, alpha, outwT);
    }
    // 3. xz GEMM (MFMA)
    {
        dim3 grid(6144 / 128, NTOK / 128);
        gemm_xz_mfma<<<grid, 256, 0, stream>>>(xnb, inwT, xi, sz);
    }
    // 4. conv + silu (float4 vectorized)
    {
        size_t total = (size_t)2 * NTOK * (DINNER / 4);
        conv_silu<<<(total + 255) / 256, 256, 0, stream>>>(xi, f_cw, f_cb, b_cw, b_cb, xc);
    }
    // 5. bcdt split-K GEMM + reduce
    {
        dim3 g(2 * NTOK / 64, KSPLIT);
        bcdt_gemm<<<g, 256, 0, stream>>>(xc, f_xw, b_xw, bcdt_part);
        bcdt_reduce<<<(2 * NTOK * NBCDT + 255) / 256, 256, 0, stream>>>(bcdt_part, bcdt);
    }
    // 6. chunked scan (thread-per-channel, TC=64 -> 768 blocks/phase)
    {
        dim3 grid1(DINNER / 256, NCHUNK, 4);
        scan_p1<<<grid1, 256, 0, stream>>>(xc, bcdt,
                                           f_dtw, f_dtb, f_Alog,
                                           b_dtw, b_dtb, b_Alog, Pbuf, hloc);
        scan_p2<<<(4 * DINNER * NSTATE) / 256, 256, 0, stream>>>(Pbuf, hloc, hin);
        scan_p3<<<grid1, 256, 0, stream>>>(xc, bcdt, sz, hin,
                                           f_dtw, f_dtb, f_Alog, f_D,
                                           b_dtw, b_dtb, b_Alog, b_D, yvb);
    }
    // 7. out GEMM (MFMA) + residual
    {
        dim3 grid(DMODEL / 64, NTOK / 128);
        gemm_out_mfma<<<grid, 256, 0, stream>>>(yvb, outwT, x, out);
    }
}